// Round 1
// baseline (1363.582 us; speedup 1.0000x reference)
//
#include <hip/hip_runtime.h>
#include <math.h>

// ---------------------------------------------------------------------------
// y[row][a] = sum_d x[row][d] * W[a][d]  (+ bias[a])      (row-major, D=64)
// One thread per row; 64 accumulators in VGPRs; W^T staged in LDS and read as
// wave-uniform broadcast float4s.
// ---------------------------------------------------------------------------
__global__ __launch_bounds__(256) void proj64(
    const float* __restrict__ x, const float* __restrict__ W,
    const float* __restrict__ bias, float* __restrict__ y, int nrows)
{
    __shared__ float wt[64][64];   // wt[d][a] = W[a][d]
    int t = threadIdx.x;
    for (int i = t; i < 4096; i += 256) wt[i & 63][i >> 6] = W[i];
    __syncthreads();

    int row = blockIdx.x * 256 + t;
    if (row >= nrows) return;

    const float4* xr = (const float4*)(x + (size_t)row * 64);
    float acc[64];
#pragma unroll
    for (int a = 0; a < 64; ++a) acc[a] = bias ? bias[a] : 0.f;

    for (int d4 = 0; d4 < 16; ++d4) {
        float4 xv = xr[d4];
#pragma unroll
        for (int dd = 0; dd < 4; ++dd) {
            int d = d4 * 4 + dd;
            float xs = (dd == 0) ? xv.x : (dd == 1) ? xv.y : (dd == 2) ? xv.z : xv.w;
#pragma unroll
            for (int a4 = 0; a4 < 16; ++a4) {
                float4 w4 = *(const float4*)&wt[d][a4 * 4];
                acc[a4 * 4 + 0] = fmaf(xs, w4.x, acc[a4 * 4 + 0]);
                acc[a4 * 4 + 1] = fmaf(xs, w4.y, acc[a4 * 4 + 1]);
                acc[a4 * 4 + 2] = fmaf(xs, w4.z, acc[a4 * 4 + 2]);
                acc[a4 * 4 + 3] = fmaf(xs, w4.w, acc[a4 * 4 + 3]);
            }
        }
    }
    float4* yr = (float4*)(y + (size_t)row * 64);
#pragma unroll
    for (int a4 = 0; a4 < 16; ++a4)
        yr[a4] = make_float4(acc[a4*4+0], acc[a4*4+1], acc[a4*4+2], acc[a4*4+3]);
}

// ---------------------------------------------------------------------------
// Fold the two (linear,linear,relu) MLP layers: Wc = w2@w1, bc = w2@b1 + b2.
// Single block, negligible cost.
// ---------------------------------------------------------------------------
__global__ __launch_bounds__(256) void combine_mlp(
    const float* __restrict__ w1, const float* __restrict__ b1,
    const float* __restrict__ w2, const float* __restrict__ b2,
    float* __restrict__ Wc, float* __restrict__ bc)
{
    __shared__ float s1[64][64];  // w1[t][k]
    __shared__ float s2[64][64];  // w2[j][t]
    int t = threadIdx.x;
    for (int i = t; i < 4096; i += 256) { s1[i >> 6][i & 63] = w1[i]; s2[i >> 6][i & 63] = w2[i]; }
    __syncthreads();
    int j = t >> 2, k0 = (t & 3) * 16;
    for (int k = k0; k < k0 + 16; ++k) {
        float a = 0.f;
        for (int tt = 0; tt < 64; ++tt) a = fmaf(s2[j][tt], s1[tt][k], a);
        Wc[j * 64 + k] = a;
    }
    if ((t & 3) == 0) {
        float a = b2[j];
        for (int tt = 0; tt < 64; ++tt) a = fmaf(s2[j][tt], b1[tt], a);
        bc[j] = a;
    }
}

// ---------------------------------------------------------------------------
// Per-edge: alpha = sigmoid(Wattn . relu(hs[sub]+rr[rel]+qq[bat]));
// scatter-add (hidden[sub]*rela[rel])*alpha into agg[obj]. 16 lanes per edge,
// one float4 per lane; 4-step shfl_xor reduce within the 16-lane group.
// ---------------------------------------------------------------------------
__global__ __launch_bounds__(256) void edge_kernel(
    const int* __restrict__ id_bat, const int* __restrict__ id_sub,
    const int* __restrict__ id_rel, const int* __restrict__ id_obj,
    const float* __restrict__ hidden, const float* __restrict__ rela,
    const float* __restrict__ hs, const float* __restrict__ rr,
    const float* __restrict__ qq, const float* __restrict__ wattn,
    float* __restrict__ agg, unsigned char* __restrict__ touched, int E)
{
    int t = threadIdx.x;
    int e = blockIdx.x * 16 + (t >> 4);
    if (e >= E) return;
    int g = t & 15;

    int sub = id_sub[e], rel = id_rel[e], bat = id_bat[e], obj = id_obj[e];

    const float4 hsv = *(const float4*)(hs     + (size_t)sub * 64 + g * 4);
    const float4 rrv = *(const float4*)(rr     + (size_t)rel * 64 + g * 4);
    const float4 qqv = *(const float4*)(qq     + (size_t)bat * 64 + g * 4);
    const float4 wv  = *(const float4*)(wattn  + g * 4);

    float c = fmaxf(hsv.x + rrv.x + qqv.x, 0.f) * wv.x
            + fmaxf(hsv.y + rrv.y + qqv.y, 0.f) * wv.y
            + fmaxf(hsv.z + rrv.z + qqv.z, 0.f) * wv.z
            + fmaxf(hsv.w + rrv.w + qqv.w, 0.f) * wv.w;
    c += __shfl_xor(c, 1);
    c += __shfl_xor(c, 2);
    c += __shfl_xor(c, 4);
    c += __shfl_xor(c, 8);
    float alpha = 1.f / (1.f + __expf(-c));

    const float4 mh = *(const float4*)(hidden + (size_t)sub * 64 + g * 4);
    const float4 mr = *(const float4*)(rela   + (size_t)rel * 64 + g * 4);

    float* ap = agg + (size_t)obj * 64 + g * 4;
    unsafeAtomicAdd(ap + 0, mh.x * mr.x * alpha);
    unsafeAtomicAdd(ap + 1, mh.y * mr.y * alpha);
    unsafeAtomicAdd(ap + 2, mh.z * mr.z * alpha);
    unsafeAtomicAdd(ap + 3, mh.w * mr.w * alpha);
    if (g == 0) touched[obj] = 1;
}

// ---------------------------------------------------------------------------
// In-place on d_out: row = touched ? relu(row @ Wc.T + bc) : 0 (already 0).
// Each row owned by exactly one thread -> read-then-write is race-free.
// ---------------------------------------------------------------------------
__global__ __launch_bounds__(256) void final_mlp(
    float* __restrict__ io, const float* __restrict__ Wc,
    const float* __restrict__ bc, const unsigned char* __restrict__ touched,
    int nrows)
{
    __shared__ float wt[64][64];   // wt[k][j] = Wc[j][k]
    int t = threadIdx.x;
    for (int i = t; i < 4096; i += 256) wt[i & 63][i >> 6] = Wc[i];
    __syncthreads();

    int row = blockIdx.x * 256 + t;
    if (row >= nrows) return;
    if (!touched[row]) return;          // agg row is all-zero from memset; output stays 0

    float4* xr = (float4*)(io + (size_t)row * 64);
    float acc[64];
#pragma unroll
    for (int a = 0; a < 64; ++a) acc[a] = bc[a];

    for (int d4 = 0; d4 < 16; ++d4) {
        float4 xv = xr[d4];
#pragma unroll
        for (int dd = 0; dd < 4; ++dd) {
            int d = d4 * 4 + dd;
            float xs = (dd == 0) ? xv.x : (dd == 1) ? xv.y : (dd == 2) ? xv.z : xv.w;
#pragma unroll
            for (int a4 = 0; a4 < 16; ++a4) {
                float4 w4 = *(const float4*)&wt[d][a4 * 4];
                acc[a4 * 4 + 0] = fmaf(xs, w4.x, acc[a4 * 4 + 0]);
                acc[a4 * 4 + 1] = fmaf(xs, w4.y, acc[a4 * 4 + 1]);
                acc[a4 * 4 + 2] = fmaf(xs, w4.z, acc[a4 * 4 + 2]);
                acc[a4 * 4 + 3] = fmaf(xs, w4.w, acc[a4 * 4 + 3]);
            }
        }
    }
#pragma unroll
    for (int a4 = 0; a4 < 16; ++a4)
        xr[a4] = make_float4(fmaxf(acc[a4*4+0], 0.f), fmaxf(acc[a4*4+1], 0.f),
                             fmaxf(acc[a4*4+2], 0.f), fmaxf(acc[a4*4+3], 0.f));
}

// ---------------------------------------------------------------------------
extern "C" void kernel_launch(void* const* d_in, const int* in_sizes, int n_in,
                              void* d_out, int out_size, void* d_ws, size_t ws_size,
                              hipStream_t stream)
{
    const float* query  = (const float*)d_in[0];
    const float* hidden = (const float*)d_in[1];
    const float* Ws     = (const float*)d_in[2];
    const float* Wr     = (const float*)d_in[3];
    const float* Wqr_w  = (const float*)d_in[4];
    const float* Wqr_b  = (const float*)d_in[5];
    const float* Wattn  = (const float*)d_in[6];
    const float* rela   = (const float*)d_in[7];
    const float* w1     = (const float*)d_in[8];
    const float* b1     = (const float*)d_in[9];
    const float* w2     = (const float*)d_in[10];
    const float* b2     = (const float*)d_in[11];
    const int* id_bat   = (const int*)d_in[12];
    const int* id_sub   = (const int*)d_in[13];
    const int* id_rel   = (const int*)d_in[14];
    const int* id_obj   = (const int*)d_in[15];

    int B  = in_sizes[0] / 64;      // 8
    int NN = in_sizes[1] / 64;      // B * N_ENT = 400000
    int NR = in_sizes[7] / 64;      // 401
    int E  = in_sizes[12];          // 1,000,000
    float* out = (float*)d_out;

    // workspace carve-up (~103 MB)
    char* ws = (char*)d_ws;
    size_t off = 0;
    auto alloc = [&](size_t bytes) { void* p = ws + off; off += (bytes + 255) & ~255ull; return p; };
    float* hs = (float*)alloc((size_t)NN * 64 * sizeof(float));
    float* rr = (float*)alloc((size_t)NR * 64 * sizeof(float));
    float* qq = (float*)alloc((size_t)B  * 64 * sizeof(float));
    float* Wc = (float*)alloc(64 * 64 * sizeof(float));
    float* bc = (float*)alloc(64 * sizeof(float));
    unsigned char* touched = (unsigned char*)alloc((size_t)NN);

    // zero the aggregation target (d_out doubles as agg) and the touched mask
    hipMemsetAsync(out, 0, (size_t)NN * 64 * sizeof(float), stream);
    hipMemsetAsync(touched, 0, (size_t)NN, stream);

    proj64<<<(NN + 255) / 256, 256, 0, stream>>>(hidden, Ws, nullptr, hs, NN);
    proj64<<<(NR + 255) / 256, 256, 0, stream>>>(rela, Wr, nullptr, rr, NR);
    proj64<<<1, 256, 0, stream>>>(query, Wqr_w, Wqr_b, qq, B);
    combine_mlp<<<1, 256, 0, stream>>>(w1, b1, w2, b2, Wc, bc);

    edge_kernel<<<(E + 15) / 16, 256, 0, stream>>>(
        id_bat, id_sub, id_rel, id_obj, hidden, rela, hs, rr, qq, Wattn,
        out, touched, E);

    final_mlp<<<(NN + 255) / 256, 256, 0, stream>>>(out, Wc, bc, touched, NN);
}

// Round 7
// 758.876 us; speedup vs baseline: 1.7968x; 1.7968x over previous
//
#include <hip/hip_runtime.h>
#include <math.h>

// ---------------------------------------------------------------------------
// y[row][a] = sum_d x[row][d] * W[a][d]  (+ bias[a])      (row-major, D=64)
// ---------------------------------------------------------------------------
__global__ __launch_bounds__(256) void proj64(
    const float* __restrict__ x, const float* __restrict__ W,
    const float* __restrict__ bias, float* __restrict__ y, int nrows)
{
    __shared__ float wt[64][64];   // wt[d][a] = W[a][d]
    int t = threadIdx.x;
    for (int i = t; i < 4096; i += 256) wt[i & 63][i >> 6] = W[i];
    __syncthreads();

    int row = blockIdx.x * 256 + t;
    if (row >= nrows) return;

    const float4* xr = (const float4*)(x + (size_t)row * 64);
    float acc[64];
#pragma unroll
    for (int a = 0; a < 64; ++a) acc[a] = bias ? bias[a] : 0.f;

    for (int d4 = 0; d4 < 16; ++d4) {
        float4 xv = xr[d4];
#pragma unroll
        for (int dd = 0; dd < 4; ++dd) {
            int d = d4 * 4 + dd;
            float xs = (dd == 0) ? xv.x : (dd == 1) ? xv.y : (dd == 2) ? xv.z : xv.w;
#pragma unroll
            for (int a4 = 0; a4 < 16; ++a4) {
                float4 w4 = *(const float4*)&wt[d][a4 * 4];
                acc[a4 * 4 + 0] = fmaf(xs, w4.x, acc[a4 * 4 + 0]);
                acc[a4 * 4 + 1] = fmaf(xs, w4.y, acc[a4 * 4 + 1]);
                acc[a4 * 4 + 2] = fmaf(xs, w4.z, acc[a4 * 4 + 2]);
                acc[a4 * 4 + 3] = fmaf(xs, w4.w, acc[a4 * 4 + 3]);
            }
        }
    }
    float4* yr = (float4*)(y + (size_t)row * 64);
#pragma unroll
    for (int a4 = 0; a4 < 16; ++a4)
        yr[a4] = make_float4(acc[a4*4+0], acc[a4*4+1], acc[a4*4+2], acc[a4*4+3]);
}

// ---------------------------------------------------------------------------
// Wc = w2@w1, bc = w2@b1 + b2 (no intermediate nonlinearity in reference MLP)
// ---------------------------------------------------------------------------
__global__ __launch_bounds__(256) void combine_mlp(
    const float* __restrict__ w1, const float* __restrict__ b1,
    const float* __restrict__ w2, const float* __restrict__ b2,
    float* __restrict__ Wc, float* __restrict__ bc)
{
    __shared__ float s1[64][64];
    __shared__ float s2[64][64];
    int t = threadIdx.x;
    for (int i = t; i < 4096; i += 256) { s1[i >> 6][i & 63] = w1[i]; s2[i >> 6][i & 63] = w2[i]; }
    __syncthreads();
    int j = t >> 2, k0 = (t & 3) * 16;
    for (int k = k0; k < k0 + 16; ++k) {
        float a = 0.f;
        for (int tt = 0; tt < 64; ++tt) a = fmaf(s2[j][tt], s1[tt][k], a);
        Wc[j * 64 + k] = a;
    }
    if ((t & 3) == 0) {
        float a = b2[j];
        for (int tt = 0; tt < 64; ++tt) a = fmaf(s2[j][tt], b1[tt], a);
        bc[j] = a;
    }
}

// ---------------------------------------------------------------------------
// CSR build step 1: histogram of id_obj
// ---------------------------------------------------------------------------
__global__ __launch_bounds__(256) void count_kernel(
    const int* __restrict__ id_obj, int* __restrict__ counts, int E)
{
    int stride = gridDim.x * blockDim.x;
    for (int e = blockIdx.x * blockDim.x + threadIdx.x; e < E; e += stride)
        atomicAdd(&counts[id_obj[e]], 1);
}

// ---------------------------------------------------------------------------
// CSR build step 2a: per-tile (1024 elems) exclusive scan; tile sums -> bsum
// ---------------------------------------------------------------------------
__global__ __launch_bounds__(256) void scan_tiles(
    const int* __restrict__ counts, int* __restrict__ offs,
    int* __restrict__ bsum, int NN)
{
    __shared__ int lsum[256];
    int t = threadIdx.x;
    int base = blockIdx.x * 1024 + t * 4;
    int c0 = 0, c1 = 0, c2 = 0, c3 = 0;
    if (base + 3 < NN) {
        int4 v = *(const int4*)(counts + base);
        c0 = v.x; c1 = v.y; c2 = v.z; c3 = v.w;
    } else {
        if (base + 0 < NN) c0 = counts[base + 0];
        if (base + 1 < NN) c1 = counts[base + 1];
        if (base + 2 < NN) c2 = counts[base + 2];
        if (base + 3 < NN) c3 = counts[base + 3];
    }
    int s = c0 + c1 + c2 + c3;
    lsum[t] = s;
    __syncthreads();
    for (int off = 1; off < 256; off <<= 1) {
        int x = (t >= off) ? lsum[t - off] : 0;
        __syncthreads();
        lsum[t] += x;
        __syncthreads();
    }
    int excl = lsum[t] - s;           // exclusive prefix within tile
    if (t == 255) bsum[blockIdx.x] = lsum[t];
    int o0 = excl, o1 = o0 + c0, o2 = o1 + c1, o3 = o2 + c2;
    if (base + 3 < NN) {
        *(int4*)(offs + base) = make_int4(o0, o1, o2, o3);
    } else {
        if (base + 0 < NN) offs[base + 0] = o0;
        if (base + 1 < NN) offs[base + 1] = o1;
        if (base + 2 < NN) offs[base + 2] = o2;
        if (base + 3 < NN) offs[base + 3] = o3;
    }
}

// ---------------------------------------------------------------------------
// CSR build step 2b: exclusive scan of tile sums (nblk <= 512, one block)
// ---------------------------------------------------------------------------
__global__ __launch_bounds__(512) void scan_bsum(int* __restrict__ bsum, int nblk)
{
    __shared__ int s[512];
    int t = threadIdx.x;
    int v = (t < nblk) ? bsum[t] : 0;
    s[t] = v;
    __syncthreads();
    for (int off = 1; off < 512; off <<= 1) {
        int x = (t >= off) ? s[t - off] : 0;
        __syncthreads();
        s[t] += x;
        __syncthreads();
    }
    if (t < nblk) bsum[t] = s[t] - v;   // exclusive
}

// ---------------------------------------------------------------------------
// CSR build step 2c: add scanned tile base; also init cursor = offs, offs[NN]=E
// ---------------------------------------------------------------------------
__global__ __launch_bounds__(256) void add_base(
    int* __restrict__ offs, int* __restrict__ cursor,
    const int* __restrict__ bsum, int NN, int E)
{
    int t = threadIdx.x;
    int base = blockIdx.x * 1024 + t * 4;
    int add = bsum[blockIdx.x];
    if (blockIdx.x == 0 && t == 0) offs[NN] = E;
#pragma unroll
    for (int k = 0; k < 4; ++k) {
        int i = base + k;
        if (i < NN) { int o = offs[i] + add; offs[i] = o; cursor[i] = o; }
    }
}

// ---------------------------------------------------------------------------
// CSR build step 3: scatter edge ids into obj-sorted order
// ---------------------------------------------------------------------------
__global__ __launch_bounds__(256) void scatter_kernel(
    const int* __restrict__ id_obj, int* __restrict__ cursor,
    int* __restrict__ sorted_e, int E)
{
    int stride = gridDim.x * blockDim.x;
    for (int e = blockIdx.x * blockDim.x + threadIdx.x; e < E; e += stride) {
        int pos = atomicAdd(&cursor[id_obj[e]], 1);
        sorted_e[pos] = e;
    }
}

// ---------------------------------------------------------------------------
// Node-centric aggregation: one 16-lane group per output node. Registers
// accumulate the float4 slice; ONE plain coalesced store per lane. No f32
// atomics anywhere.
// ---------------------------------------------------------------------------
__global__ __launch_bounds__(256) void node_kernel(
    const int* __restrict__ offs, const int* __restrict__ sorted_e,
    const int* __restrict__ id_bat, const int* __restrict__ id_sub,
    const int* __restrict__ id_rel,
    const float* __restrict__ hidden, const float* __restrict__ rela,
    const float* __restrict__ hs, const float* __restrict__ rr,
    const float* __restrict__ qq, const float* __restrict__ wattn,
    float* __restrict__ out, int NN, int B)
{
    __shared__ float sqq[8 * 64];
    int t = threadIdx.x;
    for (int i = t; i < B * 64; i += 256) sqq[i] = qq[i];
    __syncthreads();

    int g = t & 15;
    int node = blockIdx.x * 16 + (t >> 4);
    if (node >= NN) return;

    const float4 wv = *(const float4*)(wattn + g * 4);
    int beg = offs[node], end = offs[node + 1];

    float4 acc = make_float4(0.f, 0.f, 0.f, 0.f);
    for (int i = beg; i < end; ++i) {
        int e = sorted_e[i];
        int sub = id_sub[e], rel = id_rel[e], bat = id_bat[e];

        const float4 hsv = *(const float4*)(hs     + (size_t)sub * 64 + g * 4);
        const float4 rrv = *(const float4*)(rr     + (size_t)rel * 64 + g * 4);
        const float4 mh  = *(const float4*)(hidden + (size_t)sub * 64 + g * 4);
        const float4 mr  = *(const float4*)(rela   + (size_t)rel * 64 + g * 4);
        const float4 qqv = *(const float4*)&sqq[bat * 64 + g * 4];

        float c = fmaxf(hsv.x + rrv.x + qqv.x, 0.f) * wv.x
                + fmaxf(hsv.y + rrv.y + qqv.y, 0.f) * wv.y
                + fmaxf(hsv.z + rrv.z + qqv.z, 0.f) * wv.z
                + fmaxf(hsv.w + rrv.w + qqv.w, 0.f) * wv.w;
        c += __shfl_xor(c, 1);
        c += __shfl_xor(c, 2);
        c += __shfl_xor(c, 4);
        c += __shfl_xor(c, 8);
        float alpha = 1.f / (1.f + __expf(-c));

        acc.x = fmaf(mh.x * mr.x, alpha, acc.x);
        acc.y = fmaf(mh.y * mr.y, alpha, acc.y);
        acc.z = fmaf(mh.z * mr.z, alpha, acc.z);
        acc.w = fmaf(mh.w * mr.w, alpha, acc.w);
    }
    // every row gets written (zeros for deg-0) -> no d_out memset needed
    *(float4*)(out + (size_t)node * 64 + g * 4) = acc;
}

// ---------------------------------------------------------------------------
// In-place: row = (deg>0) ? relu(row @ Wc.T + bc) : row (already 0)
// ---------------------------------------------------------------------------
__global__ __launch_bounds__(256) void final_mlp(
    float* __restrict__ io, const float* __restrict__ Wc,
    const float* __restrict__ bc, const int* __restrict__ offs,
    int nrows)
{
    __shared__ float wt[64][64];
    int t = threadIdx.x;
    for (int i = t; i < 4096; i += 256) wt[i & 63][i >> 6] = Wc[i];
    __syncthreads();

    int row = blockIdx.x * 256 + t;
    if (row >= nrows) return;
    if (offs[row] == offs[row + 1]) return;   // untouched: stays exactly zero

    float4* xr = (float4*)(io + (size_t)row * 64);
    float acc[64];
#pragma unroll
    for (int a = 0; a < 64; ++a) acc[a] = bc[a];

    for (int d4 = 0; d4 < 16; ++d4) {
        float4 xv = xr[d4];
#pragma unroll
        for (int dd = 0; dd < 4; ++dd) {
            int d = d4 * 4 + dd;
            float xs = (dd == 0) ? xv.x : (dd == 1) ? xv.y : (dd == 2) ? xv.z : xv.w;
#pragma unroll
            for (int a4 = 0; a4 < 16; ++a4) {
                float4 w4 = *(const float4*)&wt[d][a4 * 4];
                acc[a4 * 4 + 0] = fmaf(xs, w4.x, acc[a4 * 4 + 0]);
                acc[a4 * 4 + 1] = fmaf(xs, w4.y, acc[a4 * 4 + 1]);
                acc[a4 * 4 + 2] = fmaf(xs, w4.z, acc[a4 * 4 + 2]);
                acc[a4 * 4 + 3] = fmaf(xs, w4.w, acc[a4 * 4 + 3]);
            }
        }
    }
#pragma unroll
    for (int a4 = 0; a4 < 16; ++a4)
        xr[a4] = make_float4(fmaxf(acc[a4*4+0], 0.f), fmaxf(acc[a4*4+1], 0.f),
                             fmaxf(acc[a4*4+2], 0.f), fmaxf(acc[a4*4+3], 0.f));
}

// ---------------------------------------------------------------------------
extern "C" void kernel_launch(void* const* d_in, const int* in_sizes, int n_in,
                              void* d_out, int out_size, void* d_ws, size_t ws_size,
                              hipStream_t stream)
{
    const float* query  = (const float*)d_in[0];
    const float* hidden = (const float*)d_in[1];
    const float* Ws     = (const float*)d_in[2];
    const float* Wr     = (const float*)d_in[3];
    const float* Wqr_w  = (const float*)d_in[4];
    const float* Wqr_b  = (const float*)d_in[5];
    const float* Wattn  = (const float*)d_in[6];
    const float* rela   = (const float*)d_in[7];
    const float* w1     = (const float*)d_in[8];
    const float* b1     = (const float*)d_in[9];
    const float* w2     = (const float*)d_in[10];
    const float* b2     = (const float*)d_in[11];
    const int* id_bat   = (const int*)d_in[12];
    const int* id_sub   = (const int*)d_in[13];
    const int* id_rel   = (const int*)d_in[14];
    const int* id_obj   = (const int*)d_in[15];

    int B  = in_sizes[0] / 64;      // 8
    int NN = in_sizes[1] / 64;      // 400000
    int NR = in_sizes[7] / 64;      // 401
    int E  = in_sizes[12];          // 1,000,000
    float* out = (float*)d_out;

    int NBLK = (NN + 1023) / 1024;  // scan tiles (must be <= 512)

    char* ws = (char*)d_ws;
    size_t off = 0;
    auto alloc = [&](size_t bytes) { void* p = ws + off; off += (bytes + 255) & ~255ull; return p; };
    float* hs      = (float*)alloc((size_t)NN * 64 * sizeof(float));
    float* rr      = (float*)alloc((size_t)NR * 64 * sizeof(float));
    float* qq      = (float*)alloc((size_t)B  * 64 * sizeof(float));
    float* Wc      = (float*)alloc(64 * 64 * sizeof(float));
    float* bc      = (float*)alloc(64 * sizeof(float));
    int*   counts  = (int*)alloc((size_t)NN * sizeof(int));      // reused as cursor
    int*   offs    = (int*)alloc(((size_t)NN + 1) * sizeof(int));
    int*   bsum    = (int*)alloc((size_t)NBLK * sizeof(int));
    int*   sorted  = (int*)alloc((size_t)E * sizeof(int));

    hipMemsetAsync(counts, 0, (size_t)NN * sizeof(int), stream);

    // projections + folded MLP weights
    proj64<<<(NN + 255) / 256, 256, 0, stream>>>(hidden, Ws, nullptr, hs, NN);
    proj64<<<(NR + 255) / 256, 256, 0, stream>>>(rela, Wr, nullptr, rr, NR);
    proj64<<<1, 256, 0, stream>>>(query, Wqr_w, Wqr_b, qq, B);
    combine_mlp<<<1, 256, 0, stream>>>(w1, b1, w2, b2, Wc, bc);

    // CSR by obj
    count_kernel<<<1024, 256, 0, stream>>>(id_obj, counts, E);
    scan_tiles<<<NBLK, 256, 0, stream>>>(counts, offs, bsum, NN);
    scan_bsum<<<1, 512, 0, stream>>>(bsum, NBLK);
    add_base<<<NBLK, 256, 0, stream>>>(offs, counts /*cursor*/, bsum, NN, E);
    scatter_kernel<<<1024, 256, 0, stream>>>(id_obj, counts /*cursor*/, sorted, E);

    // node-centric aggregation (no f32 atomics), then folded MLP
    node_kernel<<<(NN + 15) / 16, 256, 0, stream>>>(
        offs, sorted, id_bat, id_sub, id_rel, hidden, rela, hs, rr, qq, Wattn,
        out, NN, B);
    final_mlp<<<(NN + 255) / 256, 256, 0, stream>>>(out, Wc, bc, offs, NN);
}

// Round 8
// 745.420 us; speedup vs baseline: 1.8293x; 1.0181x over previous
//
#include <hip/hip_runtime.h>
#include <math.h>

// ---------------------------------------------------------------------------
// y[row][a] = sum_d x[row][d] * W[a][d]  (+ bias[a])   (row-major, D=64)
// 2 rows per thread: each LDS float4 read feeds 8 FMAs (was 4) -> no longer
// LDS-read-bound.
// ---------------------------------------------------------------------------
__global__ __launch_bounds__(256) void proj64x2(
    const float* __restrict__ x, const float* __restrict__ W,
    const float* __restrict__ bias, float* __restrict__ y, int nrows)
{
    __shared__ float wt[64][64];   // wt[d][a] = W[a][d]
    int t = threadIdx.x;
    for (int i = t; i < 4096; i += 256) wt[i & 63][i >> 6] = W[i];
    __syncthreads();

    int r0 = blockIdx.x * 512 + t;
    int r1 = r0 + 256;
    if (r0 >= nrows) return;                 // r1 > r0, so r1 also out
    bool h1 = r1 < nrows;

    const float4* x0 = (const float4*)(x + (size_t)r0 * 64);
    const float4* x1 = (const float4*)(x + (size_t)r1 * 64);

    float a0[64], a1[64];
#pragma unroll
    for (int a = 0; a < 64; ++a) { float b = bias ? bias[a] : 0.f; a0[a] = b; a1[a] = b; }

    for (int d4 = 0; d4 < 16; ++d4) {
        float4 f0 = x0[d4];
        float4 f1 = h1 ? x1[d4] : make_float4(0.f, 0.f, 0.f, 0.f);
#pragma unroll
        for (int dd = 0; dd < 4; ++dd) {
            int d = d4 * 4 + dd;
            float s0 = (dd == 0) ? f0.x : (dd == 1) ? f0.y : (dd == 2) ? f0.z : f0.w;
            float s1 = (dd == 0) ? f1.x : (dd == 1) ? f1.y : (dd == 2) ? f1.z : f1.w;
#pragma unroll
            for (int a4 = 0; a4 < 16; ++a4) {
                float4 w4 = *(const float4*)&wt[d][a4 * 4];
                a0[a4*4+0] = fmaf(s0, w4.x, a0[a4*4+0]);
                a0[a4*4+1] = fmaf(s0, w4.y, a0[a4*4+1]);
                a0[a4*4+2] = fmaf(s0, w4.z, a0[a4*4+2]);
                a0[a4*4+3] = fmaf(s0, w4.w, a0[a4*4+3]);
                a1[a4*4+0] = fmaf(s1, w4.x, a1[a4*4+0]);
                a1[a4*4+1] = fmaf(s1, w4.y, a1[a4*4+1]);
                a1[a4*4+2] = fmaf(s1, w4.z, a1[a4*4+2]);
                a1[a4*4+3] = fmaf(s1, w4.w, a1[a4*4+3]);
            }
        }
    }
    float4* y0 = (float4*)(y + (size_t)r0 * 64);
#pragma unroll
    for (int a4 = 0; a4 < 16; ++a4)
        y0[a4] = make_float4(a0[a4*4+0], a0[a4*4+1], a0[a4*4+2], a0[a4*4+3]);
    if (h1) {
        float4* y1 = (float4*)(y + (size_t)r1 * 64);
#pragma unroll
        for (int a4 = 0; a4 < 16; ++a4)
            y1[a4] = make_float4(a1[a4*4+0], a1[a4*4+1], a1[a4*4+2], a1[a4*4+3]);
    }
}

// ---------------------------------------------------------------------------
// Wc = w2@w1, bc = w2@b1 + b2 (no intermediate nonlinearity in reference MLP)
// ---------------------------------------------------------------------------
__global__ __launch_bounds__(256) void combine_mlp(
    const float* __restrict__ w1, const float* __restrict__ b1,
    const float* __restrict__ w2, const float* __restrict__ b2,
    float* __restrict__ Wc, float* __restrict__ bc)
{
    __shared__ float s1[64][64];
    __shared__ float s2[64][64];
    int t = threadIdx.x;
    for (int i = t; i < 4096; i += 256) { s1[i >> 6][i & 63] = w1[i]; s2[i >> 6][i & 63] = w2[i]; }
    __syncthreads();
    int j = t >> 2, k0 = (t & 3) * 16;
    for (int k = k0; k < k0 + 16; ++k) {
        float a = 0.f;
        for (int tt = 0; tt < 64; ++tt) a = fmaf(s2[j][tt], s1[tt][k], a);
        Wc[j * 64 + k] = a;
    }
    if ((t & 3) == 0) {
        float a = b2[j];
        for (int tt = 0; tt < 64; ++tt) a = fmaf(s2[j][tt], b1[tt], a);
        bc[j] = a;
    }
}

// ---------------------------------------------------------------------------
// CSR build step 1: histogram of id_obj
// ---------------------------------------------------------------------------
__global__ __launch_bounds__(256) void count_kernel(
    const int* __restrict__ id_obj, int* __restrict__ counts, int E)
{
    int stride = gridDim.x * blockDim.x;
    for (int e = blockIdx.x * blockDim.x + threadIdx.x; e < E; e += stride)
        atomicAdd(&counts[id_obj[e]], 1);
}

// ---------------------------------------------------------------------------
// CSR build step 2a: per-tile (1024 elems) exclusive scan; tile sums -> bsum
// ---------------------------------------------------------------------------
__global__ __launch_bounds__(256) void scan_tiles(
    const int* __restrict__ counts, int* __restrict__ offs,
    int* __restrict__ bsum, int NN)
{
    __shared__ int lsum[256];
    int t = threadIdx.x;
    int base = blockIdx.x * 1024 + t * 4;
    int c0 = 0, c1 = 0, c2 = 0, c3 = 0;
    if (base + 3 < NN) {
        int4 v = *(const int4*)(counts + base);
        c0 = v.x; c1 = v.y; c2 = v.z; c3 = v.w;
    } else {
        if (base + 0 < NN) c0 = counts[base + 0];
        if (base + 1 < NN) c1 = counts[base + 1];
        if (base + 2 < NN) c2 = counts[base + 2];
        if (base + 3 < NN) c3 = counts[base + 3];
    }
    int s = c0 + c1 + c2 + c3;
    lsum[t] = s;
    __syncthreads();
    for (int off = 1; off < 256; off <<= 1) {
        int x = (t >= off) ? lsum[t - off] : 0;
        __syncthreads();
        lsum[t] += x;
        __syncthreads();
    }
    int excl = lsum[t] - s;
    if (t == 255) bsum[blockIdx.x] = lsum[t];
    int o0 = excl, o1 = o0 + c0, o2 = o1 + c1, o3 = o2 + c2;
    if (base + 3 < NN) {
        *(int4*)(offs + base) = make_int4(o0, o1, o2, o3);
    } else {
        if (base + 0 < NN) offs[base + 0] = o0;
        if (base + 1 < NN) offs[base + 1] = o1;
        if (base + 2 < NN) offs[base + 2] = o2;
        if (base + 3 < NN) offs[base + 3] = o3;
    }
}

// ---------------------------------------------------------------------------
// CSR build step 2b: exclusive scan of tile sums (nblk <= 512, one block)
// ---------------------------------------------------------------------------
__global__ __launch_bounds__(512) void scan_bsum(int* __restrict__ bsum, int nblk)
{
    __shared__ int s[512];
    int t = threadIdx.x;
    int v = (t < nblk) ? bsum[t] : 0;
    s[t] = v;
    __syncthreads();
    for (int off = 1; off < 512; off <<= 1) {
        int x = (t >= off) ? s[t - off] : 0;
        __syncthreads();
        s[t] += x;
        __syncthreads();
    }
    if (t < nblk) bsum[t] = s[t] - v;
}

// ---------------------------------------------------------------------------
// CSR build step 2c: add scanned tile base; also init cursor = offs, offs[NN]=E
// ---------------------------------------------------------------------------
__global__ __launch_bounds__(256) void add_base(
    int* __restrict__ offs, int* __restrict__ cursor,
    const int* __restrict__ bsum, int NN, int E)
{
    int t = threadIdx.x;
    int base = blockIdx.x * 1024 + t * 4;
    int add = bsum[blockIdx.x];
    if (blockIdx.x == 0 && t == 0) offs[NN] = E;
#pragma unroll
    for (int k = 0; k < 4; ++k) {
        int i = base + k;
        if (i < NN) { int o = offs[i] + add; offs[i] = o; cursor[i] = o; }
    }
}

// ---------------------------------------------------------------------------
// CSR build step 3: scatter edge ids into obj-sorted order
// ---------------------------------------------------------------------------
__global__ __launch_bounds__(256) void scatter_kernel(
    const int* __restrict__ id_obj, int* __restrict__ cursor,
    int* __restrict__ sorted_e, int E)
{
    int stride = gridDim.x * blockDim.x;
    for (int e = blockIdx.x * blockDim.x + threadIdx.x; e < E; e += stride) {
        int pos = atomicAdd(&cursor[id_obj[e]], 1);
        sorted_e[pos] = e;
    }
}

// ---------------------------------------------------------------------------
// Node-centric aggregation + FUSED output MLP.
// One 16-lane group per node: register-accumulate the float4 slice over the
// node's CSR edge list, stage the 64-dim row in (padded) LDS, then each lane
// computes its 4 MLP outputs against Wc^T staged in LDS. One coalesced
// float4 store per lane; zero f32 atomics; no separate final_mlp pass.
// ---------------------------------------------------------------------------
__global__ __launch_bounds__(256) void node_kernel(
    const int* __restrict__ offs, const int* __restrict__ sorted_e,
    const int* __restrict__ id_bat, const int* __restrict__ id_sub,
    const int* __restrict__ id_rel,
    const float* __restrict__ hidden, const float* __restrict__ rela,
    const float* __restrict__ hs, const float* __restrict__ rr,
    const float* __restrict__ qq, const float* __restrict__ wattn,
    const float* __restrict__ Wc, const float* __restrict__ bc,
    float* __restrict__ out, int NN, int B)
{
    __shared__ float sqq[8 * 64];      // query projections (B<=8)
    __shared__ float wct[64][64];      // wct[d][a] = Wc[a][d]
    __shared__ float sbc[64];
    __shared__ float srow[16][68];     // per-group row staging, +4 pad: the
                                       // per-group broadcast read srow[grp][d]
                                       // lands on distinct banks per group
    int t = threadIdx.x;
    for (int i = t; i < B * 64; i += 256) sqq[i] = qq[i];
    for (int i = t; i < 4096; i += 256) wct[i & 63][i >> 6] = Wc[i];
    if (t < 64) sbc[t] = bc[t];
    __syncthreads();

    int g   = t & 15;
    int grp = t >> 4;
    int node = blockIdx.x * 16 + grp;
    bool valid = node < NN;
    int beg = 0, end = 0;
    if (valid) { beg = offs[node]; end = offs[node + 1]; }

    const float4 wv = *(const float4*)(wattn + g * 4);

    float4 acc = make_float4(0.f, 0.f, 0.f, 0.f);
    for (int i = beg; i < end; ++i) {
        int e = sorted_e[i];
        int sub = id_sub[e], rel = id_rel[e], bat = id_bat[e];

        const float4 hsv = *(const float4*)(hs     + (size_t)sub * 64 + g * 4);
        const float4 rrv = *(const float4*)(rr     + (size_t)rel * 64 + g * 4);
        const float4 mh  = *(const float4*)(hidden + (size_t)sub * 64 + g * 4);
        const float4 mr  = *(const float4*)(rela   + (size_t)rel * 64 + g * 4);
        const float4 qqv = *(const float4*)&sqq[bat * 64 + g * 4];

        float c = fmaxf(hsv.x + rrv.x + qqv.x, 0.f) * wv.x
                + fmaxf(hsv.y + rrv.y + qqv.y, 0.f) * wv.y
                + fmaxf(hsv.z + rrv.z + qqv.z, 0.f) * wv.z
                + fmaxf(hsv.w + rrv.w + qqv.w, 0.f) * wv.w;
        c += __shfl_xor(c, 1);
        c += __shfl_xor(c, 2);
        c += __shfl_xor(c, 4);
        c += __shfl_xor(c, 8);
        float alpha = 1.f / (1.f + __expf(-c));

        acc.x = fmaf(mh.x * mr.x, alpha, acc.x);
        acc.y = fmaf(mh.y * mr.y, alpha, acc.y);
        acc.z = fmaf(mh.z * mr.z, alpha, acc.z);
        acc.w = fmaf(mh.w * mr.w, alpha, acc.w);
    }

    // ---- fused MLP: out_row = deg>0 ? relu(agg_row @ Wc^T + bc) : 0 ----
    *(float4*)&srow[grp][g * 4] = acc;
    __syncthreads();   // all groups' rows staged (also orders LDS w->r)

    float m0 = sbc[g*4+0], m1 = sbc[g*4+1], m2 = sbc[g*4+2], m3 = sbc[g*4+3];
#pragma unroll 8
    for (int d = 0; d < 64; ++d) {
        float rv = srow[grp][d];                       // group-broadcast
        float4 w4 = *(const float4*)&wct[d][g * 4];    // 2-way (free)
        m0 = fmaf(rv, w4.x, m0);
        m1 = fmaf(rv, w4.y, m1);
        m2 = fmaf(rv, w4.z, m2);
        m3 = fmaf(rv, w4.w, m3);
    }
    if (valid) {
        float4 r;
        if (end > beg) r = make_float4(fmaxf(m0, 0.f), fmaxf(m1, 0.f),
                                       fmaxf(m2, 0.f), fmaxf(m3, 0.f));
        else           r = make_float4(0.f, 0.f, 0.f, 0.f);  // untouched: exact 0
        *(float4*)(out + (size_t)node * 64 + g * 4) = r;
    }
}

// ---------------------------------------------------------------------------
extern "C" void kernel_launch(void* const* d_in, const int* in_sizes, int n_in,
                              void* d_out, int out_size, void* d_ws, size_t ws_size,
                              hipStream_t stream)
{
    const float* query  = (const float*)d_in[0];
    const float* hidden = (const float*)d_in[1];
    const float* Ws     = (const float*)d_in[2];
    const float* Wr     = (const float*)d_in[3];
    const float* Wqr_w  = (const float*)d_in[4];
    const float* Wqr_b  = (const float*)d_in[5];
    const float* Wattn  = (const float*)d_in[6];
    const float* rela   = (const float*)d_in[7];
    const float* w1     = (const float*)d_in[8];
    const float* b1     = (const float*)d_in[9];
    const float* w2     = (const float*)d_in[10];
    const float* b2     = (const float*)d_in[11];
    const int* id_bat   = (const int*)d_in[12];
    const int* id_sub   = (const int*)d_in[13];
    const int* id_rel   = (const int*)d_in[14];
    const int* id_obj   = (const int*)d_in[15];

    int B  = in_sizes[0] / 64;      // 8
    int NN = in_sizes[1] / 64;      // 400000
    int NR = in_sizes[7] / 64;      // 401
    int E  = in_sizes[12];          // 1,000,000
    float* out = (float*)d_out;

    int NBLK = (NN + 1023) / 1024;  // scan tiles (must be <= 512)

    char* ws = (char*)d_ws;
    size_t off = 0;
    auto alloc = [&](size_t bytes) { void* p = ws + off; off += (bytes + 255) & ~255ull; return p; };
    float* hs      = (float*)alloc((size_t)NN * 64 * sizeof(float));
    float* rr      = (float*)alloc((size_t)NR * 64 * sizeof(float));
    float* qq      = (float*)alloc((size_t)B  * 64 * sizeof(float));
    float* Wc      = (float*)alloc(64 * 64 * sizeof(float));
    float* bc      = (float*)alloc(64 * sizeof(float));
    int*   counts  = (int*)alloc((size_t)NN * sizeof(int));      // reused as cursor
    int*   offs    = (int*)alloc(((size_t)NN + 1) * sizeof(int));
    int*   bsum    = (int*)alloc((size_t)NBLK * sizeof(int));
    int*   sorted  = (int*)alloc((size_t)E * sizeof(int));

    hipMemsetAsync(counts, 0, (size_t)NN * sizeof(int), stream);

    // projections + folded MLP weights
    proj64x2<<<(NN + 511) / 512, 256, 0, stream>>>(hidden, Ws, nullptr, hs, NN);
    proj64x2<<<(NR + 511) / 512, 256, 0, stream>>>(rela, Wr, nullptr, rr, NR);
    proj64x2<<<1, 256, 0, stream>>>(query, Wqr_w, Wqr_b, qq, B);
    combine_mlp<<<1, 256, 0, stream>>>(w1, b1, w2, b2, Wc, bc);

    // CSR by obj
    count_kernel<<<1024, 256, 0, stream>>>(id_obj, counts, E);
    scan_tiles<<<NBLK, 256, 0, stream>>>(counts, offs, bsum, NN);
    scan_bsum<<<1, 512, 0, stream>>>(bsum, NBLK);
    add_base<<<NBLK, 256, 0, stream>>>(offs, counts /*cursor*/, bsum, NN, E);
    scatter_kernel<<<1024, 256, 0, stream>>>(id_obj, counts /*cursor*/, sorted, E);

    // node-centric aggregation with fused output MLP (no f32 atomics)
    node_kernel<<<(NN + 15) / 16, 256, 0, stream>>>(
        offs, sorted, id_bat, id_sub, id_rel, hidden, rela, hs, rr, qq, Wattn,
        Wc, bc, out, NN, B);
}

// Round 9
// 664.113 us; speedup vs baseline: 2.0532x; 1.1224x over previous
//
#include <hip/hip_runtime.h>
#include <math.h>

// ---------------------------------------------------------------------------
// y[row][a] = sum_d x[row][d] * W[a][d]  (+ bias[a])   (row-major, D=64)
// 2 rows per thread: each LDS float4 read feeds 8 FMAs.
// ---------------------------------------------------------------------------
__global__ __launch_bounds__(256) void proj64x2(
    const float* __restrict__ x, const float* __restrict__ W,
    const float* __restrict__ bias, float* __restrict__ y, int nrows)
{
    __shared__ float wt[64][64];   // wt[d][a] = W[a][d]
    int t = threadIdx.x;
    for (int i = t; i < 4096; i += 256) wt[i & 63][i >> 6] = W[i];
    __syncthreads();

    int r0 = blockIdx.x * 512 + t;
    int r1 = r0 + 256;
    if (r0 >= nrows) return;
    bool h1 = r1 < nrows;

    const float4* x0 = (const float4*)(x + (size_t)r0 * 64);
    const float4* x1 = (const float4*)(x + (size_t)r1 * 64);

    float a0[64], a1[64];
#pragma unroll
    for (int a = 0; a < 64; ++a) { float b = bias ? bias[a] : 0.f; a0[a] = b; a1[a] = b; }

    for (int d4 = 0; d4 < 16; ++d4) {
        float4 f0 = x0[d4];
        float4 f1 = h1 ? x1[d4] : make_float4(0.f, 0.f, 0.f, 0.f);
#pragma unroll
        for (int dd = 0; dd < 4; ++dd) {
            int d = d4 * 4 + dd;
            float s0 = (dd == 0) ? f0.x : (dd == 1) ? f0.y : (dd == 2) ? f0.z : f0.w;
            float s1 = (dd == 0) ? f1.x : (dd == 1) ? f1.y : (dd == 2) ? f1.z : f1.w;
#pragma unroll
            for (int a4 = 0; a4 < 16; ++a4) {
                float4 w4 = *(const float4*)&wt[d][a4 * 4];
                a0[a4*4+0] = fmaf(s0, w4.x, a0[a4*4+0]);
                a0[a4*4+1] = fmaf(s0, w4.y, a0[a4*4+1]);
                a0[a4*4+2] = fmaf(s0, w4.z, a0[a4*4+2]);
                a0[a4*4+3] = fmaf(s0, w4.w, a0[a4*4+3]);
                a1[a4*4+0] = fmaf(s1, w4.x, a1[a4*4+0]);
                a1[a4*4+1] = fmaf(s1, w4.y, a1[a4*4+1]);
                a1[a4*4+2] = fmaf(s1, w4.z, a1[a4*4+2]);
                a1[a4*4+3] = fmaf(s1, w4.w, a1[a4*4+3]);
            }
        }
    }
    float4* y0 = (float4*)(y + (size_t)r0 * 64);
#pragma unroll
    for (int a4 = 0; a4 < 16; ++a4)
        y0[a4] = make_float4(a0[a4*4+0], a0[a4*4+1], a0[a4*4+2], a0[a4*4+3]);
    if (h1) {
        float4* y1 = (float4*)(y + (size_t)r1 * 64);
#pragma unroll
        for (int a4 = 0; a4 < 16; ++a4)
            y1[a4] = make_float4(a1[a4*4+0], a1[a4*4+1], a1[a4*4+2], a1[a4*4+3]);
    }
}

// ---------------------------------------------------------------------------
// Wc = w2@w1, bc = w2@b1 + b2; ALSO emits WcT[d][a] = Wc[a][d] so the hot
// kernel can stage it linearly (the in-kernel transpose write was a 64-way
// LDS bank conflict = 162us, R8 post-mortem).
// ---------------------------------------------------------------------------
__global__ __launch_bounds__(256) void combine_mlp(
    const float* __restrict__ w1, const float* __restrict__ b1,
    const float* __restrict__ w2, const float* __restrict__ b2,
    float* __restrict__ Wc, float* __restrict__ WcT, float* __restrict__ bc)
{
    __shared__ float s1[64][64];
    __shared__ float s2[64][64];
    int t = threadIdx.x;
    for (int i = t; i < 4096; i += 256) { s1[i >> 6][i & 63] = w1[i]; s2[i >> 6][i & 63] = w2[i]; }
    __syncthreads();
    int j = t >> 2, k0 = (t & 3) * 16;
    for (int k = k0; k < k0 + 16; ++k) {
        float a = 0.f;
        for (int tt = 0; tt < 64; ++tt) a = fmaf(s2[j][tt], s1[tt][k], a);
        Wc[j * 64 + k]  = a;
        WcT[k * 64 + j] = a;
    }
    if ((t & 3) == 0) {
        float a = b2[j];
        for (int tt = 0; tt < 64; ++tt) a = fmaf(s2[j][tt], b1[tt], a);
        bc[j] = a;
    }
}

// ---------------------------------------------------------------------------
// CSR build step 1: histogram of id_obj
// ---------------------------------------------------------------------------
__global__ __launch_bounds__(256) void count_kernel(
    const int* __restrict__ id_obj, int* __restrict__ counts, int E)
{
    int stride = gridDim.x * blockDim.x;
    for (int e = blockIdx.x * blockDim.x + threadIdx.x; e < E; e += stride)
        atomicAdd(&counts[id_obj[e]], 1);
}

// ---------------------------------------------------------------------------
// CSR build step 2a: per-tile (1024 elems) exclusive scan; tile sums -> bsum
// ---------------------------------------------------------------------------
__global__ __launch_bounds__(256) void scan_tiles(
    const int* __restrict__ counts, int* __restrict__ offs,
    int* __restrict__ bsum, int NN)
{
    __shared__ int lsum[256];
    int t = threadIdx.x;
    int base = blockIdx.x * 1024 + t * 4;
    int c0 = 0, c1 = 0, c2 = 0, c3 = 0;
    if (base + 3 < NN) {
        int4 v = *(const int4*)(counts + base);
        c0 = v.x; c1 = v.y; c2 = v.z; c3 = v.w;
    } else {
        if (base + 0 < NN) c0 = counts[base + 0];
        if (base + 1 < NN) c1 = counts[base + 1];
        if (base + 2 < NN) c2 = counts[base + 2];
        if (base + 3 < NN) c3 = counts[base + 3];
    }
    int s = c0 + c1 + c2 + c3;
    lsum[t] = s;
    __syncthreads();
    for (int off = 1; off < 256; off <<= 1) {
        int x = (t >= off) ? lsum[t - off] : 0;
        __syncthreads();
        lsum[t] += x;
        __syncthreads();
    }
    int excl = lsum[t] - s;
    if (t == 255) bsum[blockIdx.x] = lsum[t];
    int o0 = excl, o1 = o0 + c0, o2 = o1 + c1, o3 = o2 + c2;
    if (base + 3 < NN) {
        *(int4*)(offs + base) = make_int4(o0, o1, o2, o3);
    } else {
        if (base + 0 < NN) offs[base + 0] = o0;
        if (base + 1 < NN) offs[base + 1] = o1;
        if (base + 2 < NN) offs[base + 2] = o2;
        if (base + 3 < NN) offs[base + 3] = o3;
    }
}

// ---------------------------------------------------------------------------
// CSR build step 2b: exclusive scan of tile sums (nblk <= 512, one block)
// ---------------------------------------------------------------------------
__global__ __launch_bounds__(512) void scan_bsum(int* __restrict__ bsum, int nblk)
{
    __shared__ int s[512];
    int t = threadIdx.x;
    int v = (t < nblk) ? bsum[t] : 0;
    s[t] = v;
    __syncthreads();
    for (int off = 1; off < 512; off <<= 1) {
        int x = (t >= off) ? s[t - off] : 0;
        __syncthreads();
        s[t] += x;
        __syncthreads();
    }
    if (t < nblk) bsum[t] = s[t] - v;
}

// ---------------------------------------------------------------------------
// CSR build step 2c: add scanned tile base; also init cursor = offs, offs[NN]=E
// ---------------------------------------------------------------------------
__global__ __launch_bounds__(256) void add_base(
    int* __restrict__ offs, int* __restrict__ cursor,
    const int* __restrict__ bsum, int NN, int E)
{
    int t = threadIdx.x;
    int base = blockIdx.x * 1024 + t * 4;
    int add = bsum[blockIdx.x];
    if (blockIdx.x == 0 && t == 0) offs[NN] = E;
#pragma unroll
    for (int k = 0; k < 4; ++k) {
        int i = base + k;
        if (i < NN) { int o = offs[i] + add; offs[i] = o; cursor[i] = o; }
    }
}

// ---------------------------------------------------------------------------
// CSR build step 3: scatter edge ids into obj-sorted order
// ---------------------------------------------------------------------------
__global__ __launch_bounds__(256) void scatter_kernel(
    const int* __restrict__ id_obj, int* __restrict__ cursor,
    int* __restrict__ sorted_e, int E)
{
    int stride = gridDim.x * blockDim.x;
    for (int e = blockIdx.x * blockDim.x + threadIdx.x; e < E; e += stride) {
        int pos = atomicAdd(&cursor[id_obj[e]], 1);
        sorted_e[pos] = e;
    }
}

// ---------------------------------------------------------------------------
// Node-centric aggregation + fused output MLP. One 16-lane group per node.
// WcT staged with a LINEAR float4 copy (conflict-free); transpose was done
// once in combine_mlp.
// ---------------------------------------------------------------------------
__global__ __launch_bounds__(256) void node_kernel(
    const int* __restrict__ offs, const int* __restrict__ sorted_e,
    const int* __restrict__ id_bat, const int* __restrict__ id_sub,
    const int* __restrict__ id_rel,
    const float* __restrict__ hidden, const float* __restrict__ rela,
    const float* __restrict__ hs, const float* __restrict__ rr,
    const float* __restrict__ qq, const float* __restrict__ wattn,
    const float* __restrict__ WcT, const float* __restrict__ bc,
    float* __restrict__ out, int NN, int B)
{
    __shared__ float sqq[8 * 64];      // query projections (B<=8)
    __shared__ float wct[64][64];      // wct[d][a] = Wc[a][d] (pre-transposed)
    __shared__ float sbc[64];
    __shared__ float srow[16][68];     // per-group row staging (+4 pad)

    int t = threadIdx.x;
    for (int i = t; i < B * 16; i += 256)              // B*64 floats as float4
        ((float4*)sqq)[i] = ((const float4*)qq)[i];
    for (int i = t; i < 1024; i += 256)                // 4096 floats as float4
        ((float4*)wct)[i] = ((const float4*)WcT)[i];   // stride-1: conflict-free
    if (t < 64) sbc[t] = bc[t];
    __syncthreads();

    int g   = t & 15;
    int grp = t >> 4;
    int node = blockIdx.x * 16 + grp;
    bool valid = node < NN;
    int beg = 0, end = 0;
    if (valid) { beg = offs[node]; end = offs[node + 1]; }

    const float4 wv = *(const float4*)(wattn + g * 4);

    float4 acc = make_float4(0.f, 0.f, 0.f, 0.f);
    for (int i = beg; i < end; ++i) {
        int e = sorted_e[i];
        int sub = id_sub[e], rel = id_rel[e], bat = id_bat[e];

        const float4 hsv = *(const float4*)(hs     + (size_t)sub * 64 + g * 4);
        const float4 rrv = *(const float4*)(rr     + (size_t)rel * 64 + g * 4);
        const float4 mh  = *(const float4*)(hidden + (size_t)sub * 64 + g * 4);
        const float4 mr  = *(const float4*)(rela   + (size_t)rel * 64 + g * 4);
        const float4 qqv = *(const float4*)&sqq[bat * 64 + g * 4];

        float c = fmaxf(hsv.x + rrv.x + qqv.x, 0.f) * wv.x
                + fmaxf(hsv.y + rrv.y + qqv.y, 0.f) * wv.y
                + fmaxf(hsv.z + rrv.z + qqv.z, 0.f) * wv.z
                + fmaxf(hsv.w + rrv.w + qqv.w, 0.f) * wv.w;
        c += __shfl_xor(c, 1);
        c += __shfl_xor(c, 2);
        c += __shfl_xor(c, 4);
        c += __shfl_xor(c, 8);
        float alpha = 1.f / (1.f + __expf(-c));

        acc.x = fmaf(mh.x * mr.x, alpha, acc.x);
        acc.y = fmaf(mh.y * mr.y, alpha, acc.y);
        acc.z = fmaf(mh.z * mr.z, alpha, acc.z);
        acc.w = fmaf(mh.w * mr.w, alpha, acc.w);
    }

    // ---- fused MLP: out_row = deg>0 ? relu(agg_row @ Wc^T + bc) : 0 ----
    *(float4*)&srow[grp][g * 4] = acc;
    __syncthreads();   // all groups staged (orders LDS w->r)

    float m0 = sbc[g*4+0], m1 = sbc[g*4+1], m2 = sbc[g*4+2], m3 = sbc[g*4+3];
#pragma unroll 8
    for (int d = 0; d < 64; ++d) {
        float rv = srow[grp][d];                       // group-broadcast (free)
        float4 w4 = *(const float4*)&wct[d][g * 4];    // 2-way (free)
        m0 = fmaf(rv, w4.x, m0);
        m1 = fmaf(rv, w4.y, m1);
        m2 = fmaf(rv, w4.z, m2);
        m3 = fmaf(rv, w4.w, m3);
    }
    if (valid) {
        float4 r;
        if (end > beg) r = make_float4(fmaxf(m0, 0.f), fmaxf(m1, 0.f),
                                       fmaxf(m2, 0.f), fmaxf(m3, 0.f));
        else           r = make_float4(0.f, 0.f, 0.f, 0.f);  // untouched: exact 0
        *(float4*)(out + (size_t)node * 64 + g * 4) = r;
    }
}

// ---------------------------------------------------------------------------
extern "C" void kernel_launch(void* const* d_in, const int* in_sizes, int n_in,
                              void* d_out, int out_size, void* d_ws, size_t ws_size,
                              hipStream_t stream)
{
    const float* query  = (const float*)d_in[0];
    const float* hidden = (const float*)d_in[1];
    const float* Ws     = (const float*)d_in[2];
    const float* Wr     = (const float*)d_in[3];
    const float* Wqr_w  = (const float*)d_in[4];
    const float* Wqr_b  = (const float*)d_in[5];
    const float* Wattn  = (const float*)d_in[6];
    const float* rela   = (const float*)d_in[7];
    const float* w1     = (const float*)d_in[8];
    const float* b1     = (const float*)d_in[9];
    const float* w2     = (const float*)d_in[10];
    const float* b2     = (const float*)d_in[11];
    const int* id_bat   = (const int*)d_in[12];
    const int* id_sub   = (const int*)d_in[13];
    const int* id_rel   = (const int*)d_in[14];
    const int* id_obj   = (const int*)d_in[15];

    int B  = in_sizes[0] / 64;      // 8
    int NN = in_sizes[1] / 64;      // 400000
    int NR = in_sizes[7] / 64;      // 401
    int E  = in_sizes[12];          // 1,000,000
    float* out = (float*)d_out;

    int NBLK = (NN + 1023) / 1024;  // scan tiles (must be <= 512)

    char* ws = (char*)d_ws;
    size_t off = 0;
    auto alloc = [&](size_t bytes) { void* p = ws + off; off += (bytes + 255) & ~255ull; return p; };
    float* hs      = (float*)alloc((size_t)NN * 64 * sizeof(float));
    float* rr      = (float*)alloc((size_t)NR * 64 * sizeof(float));
    float* qq      = (float*)alloc((size_t)B  * 64 * sizeof(float));
    float* Wc      = (float*)alloc(64 * 64 * sizeof(float));
    float* WcT     = (float*)alloc(64 * 64 * sizeof(float));
    float* bc      = (float*)alloc(64 * sizeof(float));
    int*   counts  = (int*)alloc((size_t)NN * sizeof(int));      // reused as cursor
    int*   offs    = (int*)alloc(((size_t)NN + 1) * sizeof(int));
    int*   bsum    = (int*)alloc((size_t)NBLK * sizeof(int));
    int*   sorted  = (int*)alloc((size_t)E * sizeof(int));

    hipMemsetAsync(counts, 0, (size_t)NN * sizeof(int), stream);

    // projections + folded MLP weights
    proj64x2<<<(NN + 511) / 512, 256, 0, stream>>>(hidden, Ws, nullptr, hs, NN);
    proj64x2<<<(NR + 511) / 512, 256, 0, stream>>>(rela, Wr, nullptr, rr, NR);
    proj64x2<<<1, 256, 0, stream>>>(query, Wqr_w, Wqr_b, qq, B);
    combine_mlp<<<1, 256, 0, stream>>>(w1, b1, w2, b2, Wc, WcT, bc);

    // CSR by obj
    count_kernel<<<1024, 256, 0, stream>>>(id_obj, counts, E);
    scan_tiles<<<NBLK, 256, 0, stream>>>(counts, offs, bsum, NN);
    scan_bsum<<<1, 512, 0, stream>>>(bsum, NBLK);
    add_base<<<NBLK, 256, 0, stream>>>(offs, counts /*cursor*/, bsum, NN, E);
    scatter_kernel<<<1024, 256, 0, stream>>>(id_obj, counts /*cursor*/, sorted, E);

    // node-centric aggregation with fused output MLP (no f32 atomics)
    node_kernel<<<(NN + 15) / 16, 256, 0, stream>>>(
        offs, sorted, id_bat, id_sub, id_rel, hidden, rela, hs, rr, qq, Wattn,
        WcT, bc, out, NN, B);
}

// Round 11
// 557.680 us; speedup vs baseline: 2.4451x; 1.1908x over previous
//
#include <hip/hip_runtime.h>
#include <math.h>

#define COUNT_BLOCKS 256

// ---------------------------------------------------------------------------
// proj: y[r][a] = sum_d x[r][d]*W[a][d] (+bias), rows [base, base+512).
// 4 rows x 32 cols per thread; W staged in NATURAL layout (linear copy ->
// conflict-free; the old transposed staging was a 64-way bank conflict).
// Each LDS b128 (W[a][4d..]) feeds 16 FMAs.
// ---------------------------------------------------------------------------
__device__ __forceinline__ void proj_rows(
    const float* __restrict__ x, const float* __restrict__ W,
    const float* __restrict__ bias, float* __restrict__ y,
    int base, int nrows, float* __restrict__ smem)
{
    int t = threadIdx.x;
    float4* sm4 = (float4*)smem;                    // smem[a*64+d] = W[a][d]
    for (int i = t; i < 1024; i += 256) sm4[i] = ((const float4*)W)[i];
    __syncthreads();

    int tid = t & 127;
    int c0  = (t >> 7) * 32;                        // col half
    int r0  = base + tid;                           // rows r0 + k*128
    bool v[4];
#pragma unroll
    for (int k = 0; k < 4; ++k) v[k] = (r0 + k * 128) < nrows;
    if (!v[0]) return;                              // k increasing => all invalid

    float acc[4][32];
#pragma unroll
    for (int k = 0; k < 4; ++k)
#pragma unroll
        for (int a = 0; a < 32; ++a) acc[k][a] = bias ? bias[c0 + a] : 0.f;

    for (int d4 = 0; d4 < 16; ++d4) {
        float4 xv[4];
#pragma unroll
        for (int k = 0; k < 4; ++k)
            xv[k] = v[k] ? *(const float4*)(x + (size_t)(r0 + k * 128) * 64 + d4 * 4)
                         : make_float4(0.f, 0.f, 0.f, 0.f);
#pragma unroll
        for (int a = 0; a < 32; ++a) {
            float4 w4 = sm4[(c0 + a) * 16 + d4];    // uniform addr -> broadcast
#pragma unroll
            for (int k = 0; k < 4; ++k) {
                acc[k][a] = fmaf(xv[k].x, w4.x, acc[k][a]);
                acc[k][a] = fmaf(xv[k].y, w4.y, acc[k][a]);
                acc[k][a] = fmaf(xv[k].z, w4.z, acc[k][a]);
                acc[k][a] = fmaf(xv[k].w, w4.w, acc[k][a]);
            }
        }
    }
#pragma unroll
    for (int k = 0; k < 4; ++k) if (v[k]) {
        float* yr = y + (size_t)(r0 + k * 128) * 64 + c0;
#pragma unroll
        for (int a4 = 0; a4 < 8; ++a4)
            *(float4*)(yr + a4 * 4) = make_float4(acc[k][a4*4+0], acc[k][a4*4+1],
                                                  acc[k][a4*4+2], acc[k][a4*4+3]);
    }
}

// ---------------------------------------------------------------------------
// WcT[k][j] = (w2@w1)[j][k]; bc = w2@b1 + b2. One block; w1 in LDS, w2 via L1.
// ---------------------------------------------------------------------------
__device__ __forceinline__ void combine_device(
    const float* __restrict__ w1, const float* __restrict__ b1,
    const float* __restrict__ w2, const float* __restrict__ b2,
    float* __restrict__ WcT, float* __restrict__ bc, float* __restrict__ smem)
{
    int t = threadIdx.x;
    float4* sm4 = (float4*)smem;                    // smem[tt*64+k] = w1[tt][k]
    for (int i = t; i < 1024; i += 256) sm4[i] = ((const float4*)w1)[i];
    __syncthreads();
    int j = t >> 2, k0 = (t & 3) * 16;
    for (int k = k0; k < k0 + 16; ++k) {
        float a = 0.f;
        for (int tt = 0; tt < 64; ++tt)
            a = fmaf(w2[j * 64 + tt], smem[tt * 64 + k], a);
        WcT[k * 64 + j] = a;
    }
    if ((t & 3) == 0) {
        float a = b2[j];
        for (int tt = 0; tt < 64; ++tt) a = fmaf(w2[j * 64 + tt], b1[tt], a);
        bc[j] = a;
    }
}

__device__ __forceinline__ void count_device(
    const int* __restrict__ id_obj, int* __restrict__ counts, int E, int cb)
{
    int e = cb * 256 + (int)threadIdx.x;
    int stride = COUNT_BLOCKS * 256;
    for (; e < E; e += stride) atomicAdd(&counts[id_obj[e]], 1);
}

// ---------------------------------------------------------------------------
// Mega-prepare: blocks [0,pbNN) proj hidden; pbNN: proj rela; pbNN+1: proj
// query(+bias); pbNN+2: combine; rest: count histogram. One dispatch.
// ---------------------------------------------------------------------------
__global__ __launch_bounds__(256, 1) void prepare(
    const float* __restrict__ hidden, const float* __restrict__ Ws,
    float* __restrict__ hs, int NN, int pbNN,
    const float* __restrict__ rela, const float* __restrict__ Wr,
    float* __restrict__ rr, int NR,
    const float* __restrict__ query, const float* __restrict__ Wqr_w,
    const float* __restrict__ Wqr_b, float* __restrict__ qq, int B,
    const float* __restrict__ w1, const float* __restrict__ b1,
    const float* __restrict__ w2, const float* __restrict__ b2,
    float* __restrict__ WcT, float* __restrict__ bc,
    const int* __restrict__ id_obj, int* __restrict__ counts, int E)
{
    __shared__ float smem[4096];
    int bid = blockIdx.x;
    if      (bid <  pbNN)     proj_rows(hidden, Ws,   nullptr, hs, bid * 512, NN, smem);
    else if (bid == pbNN)     proj_rows(rela,   Wr,   nullptr, rr, 0, NR, smem);
    else if (bid == pbNN + 1) proj_rows(query,  Wqr_w, Wqr_b,  qq, 0, B,  smem);
    else if (bid == pbNN + 2) combine_device(w1, b1, w2, b2, WcT, bc, smem);
    else                      count_device(id_obj, counts, E, bid - (pbNN + 3));
}

// ---------------------------------------------------------------------------
// CSR scan step 1: per-tile (1024) exclusive scan; tile sums -> bsum
// ---------------------------------------------------------------------------
__global__ __launch_bounds__(256) void scan_tiles(
    const int* __restrict__ counts, int* __restrict__ offs,
    int* __restrict__ bsum, int NN)
{
    __shared__ int lsum[256];
    int t = threadIdx.x;
    int base = blockIdx.x * 1024 + t * 4;
    int c0 = 0, c1 = 0, c2 = 0, c3 = 0;
    if (base + 3 < NN) {
        int4 v = *(const int4*)(counts + base);
        c0 = v.x; c1 = v.y; c2 = v.z; c3 = v.w;
    } else {
        if (base + 0 < NN) c0 = counts[base + 0];
        if (base + 1 < NN) c1 = counts[base + 1];
        if (base + 2 < NN) c2 = counts[base + 2];
        if (base + 3 < NN) c3 = counts[base + 3];
    }
    int s = c0 + c1 + c2 + c3;
    lsum[t] = s;
    __syncthreads();
    for (int off = 1; off < 256; off <<= 1) {
        int x = (t >= off) ? lsum[t - off] : 0;
        __syncthreads();
        lsum[t] += x;
        __syncthreads();
    }
    int excl = lsum[t] - s;
    if (t == 255) bsum[blockIdx.x] = lsum[t];
    int o0 = excl, o1 = o0 + c0, o2 = o1 + c1, o3 = o2 + c2;
    if (base + 3 < NN) {
        *(int4*)(offs + base) = make_int4(o0, o1, o2, o3);
    } else {
        if (base + 0 < NN) offs[base + 0] = o0;
        if (base + 1 < NN) offs[base + 1] = o1;
        if (base + 2 < NN) offs[base + 2] = o2;
        if (base + 3 < NN) offs[base + 3] = o3;
    }
}

// ---------------------------------------------------------------------------
// CSR scan step 2 (fused): every block redundantly scans bsum (<=512 tiles),
// adds its tile base, inits cursor, sets offs[NN]=E.
// ---------------------------------------------------------------------------
__global__ __launch_bounds__(512) void finalize_offs(
    int* __restrict__ offs, int* __restrict__ cursor,
    const int* __restrict__ bsum, int nblk, int NN, int E)
{
    __shared__ int s[512];
    int t = threadIdx.x;
    int v = (t < nblk) ? bsum[t] : 0;
    s[t] = v;
    __syncthreads();
    for (int off = 1; off < 512; off <<= 1) {
        int x = (t >= off) ? s[t - off] : 0;
        __syncthreads();
        s[t] += x;
        __syncthreads();
    }
    int bid = blockIdx.x;
    int base = s[bid] - bsum[bid];            // exclusive prefix for this tile
    if (bid == 0 && t == 0) offs[NN] = E;
#pragma unroll
    for (int j = 0; j < 2; ++j) {
        int i = bid * 1024 + j * 512 + t;
        if (i < NN) { int o = offs[i] + base; offs[i] = o; cursor[i] = o; }
    }
}

// ---------------------------------------------------------------------------
// Scatter PACKED edge records (sub, rel, bat) into obj-sorted order.
// Removes one level of indirection from the hot node loop.
// ---------------------------------------------------------------------------
__global__ __launch_bounds__(256) void scatter_pack(
    const int* __restrict__ id_obj, const int* __restrict__ id_sub,
    const int* __restrict__ id_rel, const int* __restrict__ id_bat,
    int* __restrict__ cursor, int4* __restrict__ packed, int E)
{
    int stride = gridDim.x * blockDim.x;
    for (int e = blockIdx.x * blockDim.x + threadIdx.x; e < E; e += stride) {
        int pos = atomicAdd(&cursor[id_obj[e]], 1);
        packed[pos] = make_int4(id_sub[e], id_rel[e], id_bat[e], 0);
    }
}

// ---------------------------------------------------------------------------
// Node-centric aggregation + fused output MLP. 16-lane group per node.
// 2-edge unrolled walk over packed records; srow staging is wave-local so no
// barrier between edge loop and MLP tail (no cross-wave straggler coupling).
// ---------------------------------------------------------------------------
__global__ __launch_bounds__(256) void node_kernel(
    const int* __restrict__ offs, const int4* __restrict__ packed,
    const float* __restrict__ hidden, const float* __restrict__ rela,
    const float* __restrict__ hs, const float* __restrict__ rr,
    const float* __restrict__ qq, const float* __restrict__ wattn,
    const float* __restrict__ WcT, const float* __restrict__ bc,
    float* __restrict__ out, int NN, int B)
{
    __shared__ float sqq[8 * 64];
    __shared__ float wct[64][64];      // pre-transposed, staged linearly
    __shared__ float sbc[64];
    __shared__ float srow[16][68];     // +4 pad: per-group broadcast reads land
                                       // on distinct banks across the 4 groups
    int t = threadIdx.x;
    for (int i = t; i < B * 16; i += 256) ((float4*)sqq)[i] = ((const float4*)qq)[i];
    for (int i = t; i < 1024; i += 256) ((float4*)wct)[i] = ((const float4*)WcT)[i];
    if (t < 64) sbc[t] = bc[t];
    __syncthreads();

    int g = t & 15, grp = t >> 4;
    int node = blockIdx.x * 16 + grp;
    bool valid = node < NN;
    int beg = 0, end = 0;
    if (valid) { beg = offs[node]; end = offs[node + 1]; }
    const float4 wv = *(const float4*)(wattn + g * 4);

    float4 acc = make_float4(0.f, 0.f, 0.f, 0.f);
    int i = beg;
    for (; i + 2 <= end; i += 2) {
        int4 ra = packed[i], rb = packed[i + 1];
        const float4 hsa = *(const float4*)(hs     + (size_t)ra.x * 64 + g * 4);
        const float4 hsb = *(const float4*)(hs     + (size_t)rb.x * 64 + g * 4);
        const float4 rra = *(const float4*)(rr     + (size_t)ra.y * 64 + g * 4);
        const float4 rrb = *(const float4*)(rr     + (size_t)rb.y * 64 + g * 4);
        const float4 mha = *(const float4*)(hidden + (size_t)ra.x * 64 + g * 4);
        const float4 mhb = *(const float4*)(hidden + (size_t)rb.x * 64 + g * 4);
        const float4 mra = *(const float4*)(rela   + (size_t)ra.y * 64 + g * 4);
        const float4 mrb = *(const float4*)(rela   + (size_t)rb.y * 64 + g * 4);
        const float4 qqa = *(const float4*)&sqq[ra.z * 64 + g * 4];
        const float4 qqb = *(const float4*)&sqq[rb.z * 64 + g * 4];

        float ca = fmaxf(hsa.x + rra.x + qqa.x, 0.f) * wv.x
                 + fmaxf(hsa.y + rra.y + qqa.y, 0.f) * wv.y
                 + fmaxf(hsa.z + rra.z + qqa.z, 0.f) * wv.z
                 + fmaxf(hsa.w + rra.w + qqa.w, 0.f) * wv.w;
        float cb = fmaxf(hsb.x + rrb.x + qqb.x, 0.f) * wv.x
                 + fmaxf(hsb.y + rrb.y + qqb.y, 0.f) * wv.y
                 + fmaxf(hsb.z + rrb.z + qqb.z, 0.f) * wv.z
                 + fmaxf(hsb.w + rrb.w + qqb.w, 0.f) * wv.w;
        ca += __shfl_xor(ca, 1);  cb += __shfl_xor(cb, 1);
        ca += __shfl_xor(ca, 2);  cb += __shfl_xor(cb, 2);
        ca += __shfl_xor(ca, 4);  cb += __shfl_xor(cb, 4);
        ca += __shfl_xor(ca, 8);  cb += __shfl_xor(cb, 8);
        float aa = 1.f / (1.f + __expf(-ca));
        float ab = 1.f / (1.f + __expf(-cb));

        acc.x = fmaf(mha.x * mra.x, aa, acc.x);
        acc.y = fmaf(mha.y * mra.y, aa, acc.y);
        acc.z = fmaf(mha.z * mra.z, aa, acc.z);
        acc.w = fmaf(mha.w * mra.w, aa, acc.w);
        acc.x = fmaf(mhb.x * mrb.x, ab, acc.x);
        acc.y = fmaf(mhb.y * mrb.y, ab, acc.y);
        acc.z = fmaf(mhb.z * mrb.z, ab, acc.z);
        acc.w = fmaf(mhb.w * mrb.w, ab, acc.w);
    }
    if (i < end) {
        int4 ra = packed[i];
        const float4 hsa = *(const float4*)(hs     + (size_t)ra.x * 64 + g * 4);
        const float4 rra = *(const float4*)(rr     + (size_t)ra.y * 64 + g * 4);
        const float4 mha = *(const float4*)(hidden + (size_t)ra.x * 64 + g * 4);
        const float4 mra = *(const float4*)(rela   + (size_t)ra.y * 64 + g * 4);
        const float4 qqa = *(const float4*)&sqq[ra.z * 64 + g * 4];
        float ca = fmaxf(hsa.x + rra.x + qqa.x, 0.f) * wv.x
                 + fmaxf(hsa.y + rra.y + qqa.y, 0.f) * wv.y
                 + fmaxf(hsa.z + rra.z + qqa.z, 0.f) * wv.z
                 + fmaxf(hsa.w + rra.w + qqa.w, 0.f) * wv.w;
        ca += __shfl_xor(ca, 1);
        ca += __shfl_xor(ca, 2);
        ca += __shfl_xor(ca, 4);
        ca += __shfl_xor(ca, 8);
        float aa = 1.f / (1.f + __expf(-ca));
        acc.x = fmaf(mha.x * mra.x, aa, acc.x);
        acc.y = fmaf(mha.y * mra.y, aa, acc.y);
        acc.z = fmaf(mha.z * mra.z, aa, acc.z);
        acc.w = fmaf(mha.w * mra.w, aa, acc.w);
    }

    // ---- fused MLP (wave-local srow: no barrier) ----
    *(float4*)&srow[grp][g * 4] = acc;
    float m0 = sbc[g*4+0], m1 = sbc[g*4+1], m2 = sbc[g*4+2], m3 = sbc[g*4+3];
#pragma unroll 8
    for (int d = 0; d < 64; ++d) {
        float rv = srow[grp][d];
        float4 w4 = *(const float4*)&wct[d][g * 4];
        m0 = fmaf(rv, w4.x, m0);
        m1 = fmaf(rv, w4.y, m1);
        m2 = fmaf(rv, w4.z, m2);
        m3 = fmaf(rv, w4.w, m3);
    }
    if (valid) {
        float4 r;
        if (end > beg) r = make_float4(fmaxf(m0, 0.f), fmaxf(m1, 0.f),
                                       fmaxf(m2, 0.f), fmaxf(m3, 0.f));
        else           r = make_float4(0.f, 0.f, 0.f, 0.f);
        *(float4*)(out + (size_t)node * 64 + g * 4) = r;
    }
}

// ---------------------------------------------------------------------------
extern "C" void kernel_launch(void* const* d_in, const int* in_sizes, int n_in,
                              void* d_out, int out_size, void* d_ws, size_t ws_size,
                              hipStream_t stream)
{
    const float* query  = (const float*)d_in[0];
    const float* hidden = (const float*)d_in[1];
    const float* Ws     = (const float*)d_in[2];
    const float* Wr     = (const float*)d_in[3];
    const float* Wqr_w  = (const float*)d_in[4];
    const float* Wqr_b  = (const float*)d_in[5];
    const float* Wattn  = (const float*)d_in[6];
    const float* rela   = (const float*)d_in[7];
    const float* w1     = (const float*)d_in[8];
    const float* b1     = (const float*)d_in[9];
    const float* w2     = (const float*)d_in[10];
    const float* b2     = (const float*)d_in[11];
    const int* id_bat   = (const int*)d_in[12];
    const int* id_sub   = (const int*)d_in[13];
    const int* id_rel   = (const int*)d_in[14];
    const int* id_obj   = (const int*)d_in[15];

    int B  = in_sizes[0] / 64;      // 8
    int NN = in_sizes[1] / 64;      // 400000
    int NR = in_sizes[7] / 64;      // 401
    int E  = in_sizes[12];          // 1,000,000
    float* out = (float*)d_out;

    int NBLK = (NN + 1023) / 1024;  // scan tiles (<= 512)
    int pbNN = (NN + 511) / 512;    // proj blocks for hidden

    char* ws = (char*)d_ws;
    size_t off = 0;
    auto alloc = [&](size_t bytes) { void* p = ws + off; off += (bytes + 255) & ~255ull; return p; };
    float* hs      = (float*)alloc((size_t)NN * 64 * sizeof(float));
    float* rr      = (float*)alloc((size_t)NR * 64 * sizeof(float));
    float* qq      = (float*)alloc((size_t)B  * 64 * sizeof(float));
    float* WcT     = (float*)alloc(64 * 64 * sizeof(float));
    float* bc      = (float*)alloc(64 * sizeof(float));
    int*   counts  = (int*)alloc((size_t)NN * sizeof(int));       // reused as cursor
    int*   offs    = (int*)alloc(((size_t)NN + 1) * sizeof(int));
    int*   bsum    = (int*)alloc((size_t)NBLK * sizeof(int));
    int4*  packed  = (int4*)alloc((size_t)E * sizeof(int4));

    hipMemsetAsync(counts, 0, (size_t)NN * sizeof(int), stream);

    prepare<<<pbNN + 3 + COUNT_BLOCKS, 256, 0, stream>>>(
        hidden, Ws, hs, NN, pbNN,
        rela, Wr, rr, NR,
        query, Wqr_w, Wqr_b, qq, B,
        w1, b1, w2, b2, WcT, bc,
        id_obj, counts, E);

    scan_tiles<<<NBLK, 256, 0, stream>>>(counts, offs, bsum, NN);
    finalize_offs<<<NBLK, 512, 0, stream>>>(offs, counts /*cursor*/, bsum, NBLK, NN, E);
    scatter_pack<<<1024, 256, 0, stream>>>(id_obj, id_sub, id_rel, id_bat,
                                           counts /*cursor*/, packed, E);

    node_kernel<<<(NN + 15) / 16, 256, 0, stream>>>(
        offs, packed, hidden, rela, hs, rr, qq, Wattn, WcT, bc, out, NN, B);
}

// Round 14
// 524.155 us; speedup vs baseline: 2.6015x; 1.0640x over previous
//
#include <hip/hip_runtime.h>
#include <math.h>

#define COUNT_BLOCKS 256

// Edge record packing: sub(19b) | rel(9b)<<19 | bat(3b)<<28  (NN<2^19, NR<2^9, B<=8)

// ---------------------------------------------------------------------------
// proj: y[r][a] = sum_d x[r][d]*W[a][d] (+bias), rows [base, base+512).
// 4 rows x 32 cols per thread; W staged in NATURAL layout (conflict-free).
// ---------------------------------------------------------------------------
__device__ __forceinline__ void proj_rows(
    const float* __restrict__ x, const float* __restrict__ W,
    const float* __restrict__ bias, float* __restrict__ y,
    int base, int nrows, float* __restrict__ smem)
{
    int t = threadIdx.x;
    float4* sm4 = (float4*)smem;                    // smem[a*64+d] = W[a][d]
    for (int i = t; i < 1024; i += 256) sm4[i] = ((const float4*)W)[i];
    __syncthreads();

    int tid = t & 127;
    int c0  = (t >> 7) * 32;
    int r0  = base + tid;
    bool v[4];
#pragma unroll
    for (int k = 0; k < 4; ++k) v[k] = (r0 + k * 128) < nrows;
    if (!v[0]) return;

    float acc[4][32];
#pragma unroll
    for (int k = 0; k < 4; ++k)
#pragma unroll
        for (int a = 0; a < 32; ++a) acc[k][a] = bias ? bias[c0 + a] : 0.f;

    for (int d4 = 0; d4 < 16; ++d4) {
        float4 xv[4];
#pragma unroll
        for (int k = 0; k < 4; ++k)
            xv[k] = v[k] ? *(const float4*)(x + (size_t)(r0 + k * 128) * 64 + d4 * 4)
                         : make_float4(0.f, 0.f, 0.f, 0.f);
#pragma unroll
        for (int a = 0; a < 32; ++a) {
            float4 w4 = sm4[(c0 + a) * 16 + d4];
#pragma unroll
            for (int k = 0; k < 4; ++k) {
                acc[k][a] = fmaf(xv[k].x, w4.x, acc[k][a]);
                acc[k][a] = fmaf(xv[k].y, w4.y, acc[k][a]);
                acc[k][a] = fmaf(xv[k].z, w4.z, acc[k][a]);
                acc[k][a] = fmaf(xv[k].w, w4.w, acc[k][a]);
            }
        }
    }
#pragma unroll
    for (int k = 0; k < 4; ++k) if (v[k]) {
        float* yr = y + (size_t)(r0 + k * 128) * 64 + c0;
#pragma unroll
        for (int a4 = 0; a4 < 8; ++a4)
            *(float4*)(yr + a4 * 4) = make_float4(acc[k][a4*4+0], acc[k][a4*4+1],
                                                  acc[k][a4*4+2], acc[k][a4*4+3]);
    }
}

// ---------------------------------------------------------------------------
// WcT[k][j] = (w2@w1)[j][k]; bc = w2@b1 + b2.
// ---------------------------------------------------------------------------
__device__ __forceinline__ void combine_device(
    const float* __restrict__ w1, const float* __restrict__ b1,
    const float* __restrict__ w2, const float* __restrict__ b2,
    float* __restrict__ WcT, float* __restrict__ bc, float* __restrict__ smem)
{
    int t = threadIdx.x;
    float4* sm4 = (float4*)smem;                    // smem[tt*64+k] = w1[tt][k]
    for (int i = t; i < 1024; i += 256) sm4[i] = ((const float4*)w1)[i];
    __syncthreads();
    int j = t >> 2, k0 = (t & 3) * 16;
    for (int k = k0; k < k0 + 16; ++k) {
        float a = 0.f;
        for (int tt = 0; tt < 64; ++tt)
            a = fmaf(w2[j * 64 + tt], smem[tt * 64 + k], a);
        WcT[k * 64 + j] = a;
    }
    if ((t & 3) == 0) {
        float a = b2[j];
        for (int tt = 0; tt < 64; ++tt) a = fmaf(w2[j * 64 + tt], b1[tt], a);
        bc[j] = a;
    }
}

__device__ __forceinline__ void count_device(
    const int* __restrict__ id_obj, int* __restrict__ counts, int E, int cb)
{
    int e = cb * 256 + (int)threadIdx.x;
    int stride = COUNT_BLOCKS * 256;
    for (; e < E; e += stride) atomicAdd(&counts[id_obj[e]], 1);
}

// ---------------------------------------------------------------------------
// Mega-prepare: proj hidden / rela / query, combine MLP, count histogram.
// ---------------------------------------------------------------------------
__global__ __launch_bounds__(256, 1) void prepare(
    const float* __restrict__ hidden, const float* __restrict__ Ws,
    float* __restrict__ hs, int NN, int pbNN,
    const float* __restrict__ rela, const float* __restrict__ Wr,
    float* __restrict__ rr, int NR,
    const float* __restrict__ query, const float* __restrict__ Wqr_w,
    const float* __restrict__ Wqr_b, float* __restrict__ qq, int B,
    const float* __restrict__ w1, const float* __restrict__ b1,
    const float* __restrict__ w2, const float* __restrict__ b2,
    float* __restrict__ WcT, float* __restrict__ bc,
    const int* __restrict__ id_obj, int* __restrict__ counts, int E)
{
    __shared__ float smem[4096];
    int bid = blockIdx.x;
    if      (bid <  pbNN)     proj_rows(hidden, Ws,   nullptr, hs, bid * 512, NN, smem);
    else if (bid == pbNN)     proj_rows(rela,   Wr,   nullptr, rr, 0, NR, smem);
    else if (bid == pbNN + 1) proj_rows(query,  Wqr_w, Wqr_b,  qq, 0, B,  smem);
    else if (bid == pbNN + 2) combine_device(w1, b1, w2, b2, WcT, bc, smem);
    else                      count_device(id_obj, counts, E, bid - (pbNN + 3));
}

// ---------------------------------------------------------------------------
// CSR scan step 1: per-tile (1024) exclusive scan; tile sums -> bsum
// ---------------------------------------------------------------------------
__global__ __launch_bounds__(256) void scan_tiles(
    const int* __restrict__ counts, int* __restrict__ offs,
    int* __restrict__ bsum, int NN)
{
    __shared__ int lsum[256];
    int t = threadIdx.x;
    int base = blockIdx.x * 1024 + t * 4;
    int c0 = 0, c1 = 0, c2 = 0, c3 = 0;
    if (base + 3 < NN) {
        int4 v = *(const int4*)(counts + base);
        c0 = v.x; c1 = v.y; c2 = v.z; c3 = v.w;
    } else {
        if (base + 0 < NN) c0 = counts[base + 0];
        if (base + 1 < NN) c1 = counts[base + 1];
        if (base + 2 < NN) c2 = counts[base + 2];
        if (base + 3 < NN) c3 = counts[base + 3];
    }
    int s = c0 + c1 + c2 + c3;
    lsum[t] = s;
    __syncthreads();
    for (int off = 1; off < 256; off <<= 1) {
        int x = (t >= off) ? lsum[t - off] : 0;
        __syncthreads();
        lsum[t] += x;
        __syncthreads();
    }
    int excl = lsum[t] - s;
    if (t == 255) bsum[blockIdx.x] = lsum[t];
    int o0 = excl, o1 = o0 + c0, o2 = o1 + c1, o3 = o2 + c2;
    if (base + 3 < NN) {
        *(int4*)(offs + base) = make_int4(o0, o1, o2, o3);
    } else {
        if (base + 0 < NN) offs[base + 0] = o0;
        if (base + 1 < NN) offs[base + 1] = o1;
        if (base + 2 < NN) offs[base + 2] = o2;
        if (base + 3 < NN) offs[base + 3] = o3;
    }
}

// ---------------------------------------------------------------------------
// CSR scan step 2 (fused): redundant per-block scan of bsum; add base; init
// cursor; offs[NN]=E.
// ---------------------------------------------------------------------------
__global__ __launch_bounds__(512) void finalize_offs(
    int* __restrict__ offs, int* __restrict__ cursor,
    const int* __restrict__ bsum, int nblk, int NN, int E)
{
    __shared__ int s[512];
    int t = threadIdx.x;
    int v = (t < nblk) ? bsum[t] : 0;
    s[t] = v;
    __syncthreads();
    for (int off = 1; off < 512; off <<= 1) {
        int x = (t >= off) ? s[t - off] : 0;
        __syncthreads();
        s[t] += x;
        __syncthreads();
    }
    int bid = blockIdx.x;
    int base = s[bid] - bsum[bid];
    if (bid == 0 && t == 0) offs[NN] = E;
#pragma unroll
    for (int j = 0; j < 2; ++j) {
        int i = bid * 1024 + j * 512 + t;
        if (i < NN) { int o = offs[i] + base; offs[i] = o; cursor[i] = o; }
    }
}

// ---------------------------------------------------------------------------
// Scatter u32-PACKED edge records into obj-sorted order (4B random writes,
// was 16B).
// ---------------------------------------------------------------------------
__global__ __launch_bounds__(256) void scatter_pack(
    const int* __restrict__ id_obj, const int* __restrict__ id_sub,
    const int* __restrict__ id_rel, const int* __restrict__ id_bat,
    int* __restrict__ cursor, unsigned int* __restrict__ packed, int E)
{
    int stride = gridDim.x * blockDim.x;
    for (int e = blockIdx.x * blockDim.x + threadIdx.x; e < E; e += stride) {
        int pos = atomicAdd(&cursor[id_obj[e]], 1);
        packed[pos] = (unsigned int)id_sub[e]
                    | ((unsigned int)id_rel[e] << 19)
                    | ((unsigned int)id_bat[e] << 28);
    }
}

// ---------------------------------------------------------------------------
// Persistent node kernel: grid-stride over 16-node tiles so wct/sqq staging
// amortizes over ~6 tiles/block instead of 1. 16-lane group per node,
// 2-edge unroll (one uint2 load), fused output MLP, no f32 atomics.
// ---------------------------------------------------------------------------
__global__ __launch_bounds__(256) void node_kernel(
    const int* __restrict__ offs, const unsigned int* __restrict__ packed,
    const float* __restrict__ hidden, const float* __restrict__ rela,
    const float* __restrict__ hs, const float* __restrict__ rr,
    const float* __restrict__ qq, const float* __restrict__ wattn,
    const float* __restrict__ WcT, const float* __restrict__ bc,
    float* __restrict__ out, int NN, int B)
{
    __shared__ float sqq[8 * 64];
    __shared__ float wct[64][64];      // pre-transposed, staged linearly
    __shared__ float sbc[64];
    __shared__ float srow[16][68];     // +4 pad

    int t = threadIdx.x;
    for (int i = t; i < B * 16; i += 256) ((float4*)sqq)[i] = ((const float4*)qq)[i];
    for (int i = t; i < 1024; i += 256) ((float4*)wct)[i] = ((const float4*)WcT)[i];
    if (t < 64) sbc[t] = bc[t];
    __syncthreads();

    int g = t & 15, grp = t >> 4;
    const float4 wv = *(const float4*)(wattn + g * 4);
    float bc0 = sbc[g*4+0], bc1 = sbc[g*4+1], bc2 = sbc[g*4+2], bc3 = sbc[g*4+3];

    int ntiles = (NN + 15) / 16;
    for (int tile = blockIdx.x; tile < ntiles; tile += gridDim.x) {
        int node = tile * 16 + grp;
        bool valid = node < NN;
        int beg = 0, end = 0;
        if (valid) { beg = offs[node]; end = offs[node + 1]; }

        float4 acc = make_float4(0.f, 0.f, 0.f, 0.f);
        int i = beg;
        for (; i + 2 <= end; i += 2) {
            uint2 pr = *(const uint2*)(packed + i);
            int suba = pr.x & 0x7FFFF, rela_a = (pr.x >> 19) & 0x1FF, bata = pr.x >> 28;
            int subb = pr.y & 0x7FFFF, rela_b = (pr.y >> 19) & 0x1FF, batb = pr.y >> 28;

            const float4 hsa = *(const float4*)(hs     + (size_t)suba * 64 + g * 4);
            const float4 hsb = *(const float4*)(hs     + (size_t)subb * 64 + g * 4);
            const float4 rra = *(const float4*)(rr     + (size_t)rela_a * 64 + g * 4);
            const float4 rrb = *(const float4*)(rr     + (size_t)rela_b * 64 + g * 4);
            const float4 mha = *(const float4*)(hidden + (size_t)suba * 64 + g * 4);
            const float4 mhb = *(const float4*)(hidden + (size_t)subb * 64 + g * 4);
            const float4 mra = *(const float4*)(rela   + (size_t)rela_a * 64 + g * 4);
            const float4 mrb = *(const float4*)(rela   + (size_t)rela_b * 64 + g * 4);
            const float4 qqa = *(const float4*)&sqq[bata * 64 + g * 4];
            const float4 qqb = *(const float4*)&sqq[batb * 64 + g * 4];

            float ca = fmaxf(hsa.x + rra.x + qqa.x, 0.f) * wv.x
                     + fmaxf(hsa.y + rra.y + qqa.y, 0.f) * wv.y
                     + fmaxf(hsa.z + rra.z + qqa.z, 0.f) * wv.z
                     + fmaxf(hsa.w + rra.w + qqa.w, 0.f) * wv.w;
            float cb = fmaxf(hsb.x + rrb.x + qqb.x, 0.f) * wv.x
                     + fmaxf(hsb.y + rrb.y + qqb.y, 0.f) * wv.y
                     + fmaxf(hsb.z + rrb.z + qqb.z, 0.f) * wv.z
                     + fmaxf(hsb.w + rrb.w + qqb.w, 0.f) * wv.w;
            ca += __shfl_xor(ca, 1);  cb += __shfl_xor(cb, 1);
            ca += __shfl_xor(ca, 2);  cb += __shfl_xor(cb, 2);
            ca += __shfl_xor(ca, 4);  cb += __shfl_xor(cb, 4);
            ca += __shfl_xor(ca, 8);  cb += __shfl_xor(cb, 8);
            float aa = 1.f / (1.f + __expf(-ca));
            float ab = 1.f / (1.f + __expf(-cb));

            acc.x = fmaf(mha.x * mra.x, aa, acc.x);
            acc.y = fmaf(mha.y * mra.y, aa, acc.y);
            acc.z = fmaf(mha.z * mra.z, aa, acc.z);
            acc.w = fmaf(mha.w * mra.w, aa, acc.w);
            acc.x = fmaf(mhb.x * mrb.x, ab, acc.x);
            acc.y = fmaf(mhb.y * mrb.y, ab, acc.y);
            acc.z = fmaf(mhb.z * mrb.z, ab, acc.z);
            acc.w = fmaf(mhb.w * mrb.w, ab, acc.w);
        }
        if (i < end) {
            unsigned int p = packed[i];
            int suba = p & 0x7FFFF, rela_a = (p >> 19) & 0x1FF, bata = p >> 28;
            const float4 hsa = *(const float4*)(hs     + (size_t)suba * 64 + g * 4);
            const float4 rra = *(const float4*)(rr     + (size_t)rela_a * 64 + g * 4);
            const float4 mha = *(const float4*)(hidden + (size_t)suba * 64 + g * 4);
            const float4 mra = *(const float4*)(rela   + (size_t)rela_a * 64 + g * 4);
            const float4 qqa = *(const float4*)&sqq[bata * 64 + g * 4];
            float ca = fmaxf(hsa.x + rra.x + qqa.x, 0.f) * wv.x
                     + fmaxf(hsa.y + rra.y + qqa.y, 0.f) * wv.y
                     + fmaxf(hsa.z + rra.z + qqa.z, 0.f) * wv.z
                     + fmaxf(hsa.w + rra.w + qqa.w, 0.f) * wv.w;
            ca += __shfl_xor(ca, 1);
            ca += __shfl_xor(ca, 2);
            ca += __shfl_xor(ca, 4);
            ca += __shfl_xor(ca, 8);
            float aa = 1.f / (1.f + __expf(-ca));
            acc.x = fmaf(mha.x * mra.x, aa, acc.x);
            acc.y = fmaf(mha.y * mra.y, aa, acc.y);
            acc.z = fmaf(mha.z * mra.z, aa, acc.z);
            acc.w = fmaf(mha.w * mra.w, aa, acc.w);
        }

        // ---- fused MLP (wave-local srow: no barrier) ----
        *(float4*)&srow[grp][g * 4] = acc;
        float m0 = bc0, m1 = bc1, m2 = bc2, m3 = bc3;
#pragma unroll 8
        for (int d = 0; d < 64; ++d) {
            float rv = srow[grp][d];
            float4 w4 = *(const float4*)&wct[d][g * 4];
            m0 = fmaf(rv, w4.x, m0);
            m1 = fmaf(rv, w4.y, m1);
            m2 = fmaf(rv, w4.z, m2);
            m3 = fmaf(rv, w4.w, m3);
        }
        if (valid) {
            float4 r;
            if (end > beg) r = make_float4(fmaxf(m0, 0.f), fmaxf(m1, 0.f),
                                           fmaxf(m2, 0.f), fmaxf(m3, 0.f));
            else           r = make_float4(0.f, 0.f, 0.f, 0.f);
            *(float4*)(out + (size_t)node * 64 + g * 4) = r;
        }
    }
}

// ---------------------------------------------------------------------------
extern "C" void kernel_launch(void* const* d_in, const int* in_sizes, int n_in,
                              void* d_out, int out_size, void* d_ws, size_t ws_size,
                              hipStream_t stream)
{
    const float* query  = (const float*)d_in[0];
    const float* hidden = (const float*)d_in[1];
    const float* Ws     = (const float*)d_in[2];
    const float* Wr     = (const float*)d_in[3];
    const float* Wqr_w  = (const float*)d_in[4];
    const float* Wqr_b  = (const float*)d_in[5];
    const float* Wattn  = (const float*)d_in[6];
    const float* rela   = (const float*)d_in[7];
    const float* w1     = (const float*)d_in[8];
    const float* b1     = (const float*)d_in[9];
    const float* w2     = (const float*)d_in[10];
    const float* b2     = (const float*)d_in[11];
    const int* id_bat   = (const int*)d_in[12];
    const int* id_sub   = (const int*)d_in[13];
    const int* id_rel   = (const int*)d_in[14];
    const int* id_obj   = (const int*)d_in[15];

    int B  = in_sizes[0] / 64;      // 8
    int NN = in_sizes[1] / 64;      // 400000  (< 2^19: packing valid)
    int NR = in_sizes[7] / 64;      // 401     (< 2^9)
    int E  = in_sizes[12];          // 1,000,000
    float* out = (float*)d_out;

    int NBLK = (NN + 1023) / 1024;  // scan tiles (<= 512)
    int pbNN = (NN + 511) / 512;    // proj blocks for hidden

    char* ws = (char*)d_ws;
    size_t off = 0;
    auto alloc = [&](size_t bytes) { void* p = ws + off; off += (bytes + 255) & ~255ull; return p; };
    float*        hs     = (float*)alloc((size_t)NN * 64 * sizeof(float));
    float*        rr     = (float*)alloc((size_t)NR * 64 * sizeof(float));
    float*        qq     = (float*)alloc((size_t)B  * 64 * sizeof(float));
    float*        WcT    = (float*)alloc(64 * 64 * sizeof(float));
    float*        bc     = (float*)alloc(64 * sizeof(float));
    int*          counts = (int*)alloc((size_t)NN * sizeof(int));   // reused as cursor
    int*          offs   = (int*)alloc(((size_t)NN + 1) * sizeof(int));
    int*          bsum   = (int*)alloc((size_t)NBLK * sizeof(int));
    unsigned int* packed = (unsigned int*)alloc((size_t)E * sizeof(unsigned int));

    hipMemsetAsync(counts, 0, (size_t)NN * sizeof(int), stream);

    prepare<<<pbNN + 3 + COUNT_BLOCKS, 256, 0, stream>>>(
        hidden, Ws, hs, NN, pbNN,
        rela, Wr, rr, NR,
        query, Wqr_w, Wqr_b, qq, B,
        w1, b1, w2, b2, WcT, bc,
        id_obj, counts, E);

    scan_tiles<<<NBLK, 256, 0, stream>>>(counts, offs, bsum, NN);
    finalize_offs<<<NBLK, 512, 0, stream>>>(offs, counts /*cursor*/, bsum, NBLK, NN, E);
    scatter_pack<<<1024, 256, 0, stream>>>(id_obj, id_sub, id_rel, id_bat,
                                           counts /*cursor*/, packed, E);

    node_kernel<<<4096, 256, 0, stream>>>(
        offs, packed, hidden, rela, hs, rr, qq, Wattn, WcT, bc, out, NN, B);
}